// Round 1
// baseline (711.262 us; speedup 1.0000x reference)
//
#include <hip/hip_runtime.h>

// QANet block, fp32 baseline. B=16 D=128 LC=2048 LQ=256.
// ws layout (floats):
//   Sdot  [B][LC][LQ]   8388608   (dot-only logits, rank-1 terms added on the fly)
//   rC    [B][LC]         32768
//   rQ    [B][LQ]          4096
//   pm/pz [B][16][LQ]     65536*2  (column-softmax partials)
//   mcol/zcol [B][LQ]      4096*2
//   ScTCt [B][D][LQ]     524288   (S_col^T @ Ct, stored d-major)
//   part  [4][B][D][LQ] 2097152   (split-K partials for ScTC)
//   Abuf/Bmbuf [B][LC][D] 4194304*2
//   Wt    [4D][D]          65536   (W_res transposed)
// total ~19.64M floats = 78.6 MB

#define B_ 16
#define D_ 128
#define LC_ 2048
#define LQ_ 256
#define NEGV -1e30f

typedef float f4 __attribute__((ext_vector_type(4)));
typedef int i4 __attribute__((ext_vector_type(4)));

// r[b,pos] = sum_d w[d] * X[b,d,pos]
__global__ void k_rvec(const float* __restrict__ X, const float* __restrict__ w,
                       float* __restrict__ r, int L) {
    int g = blockIdx.x * 256 + threadIdx.x;
    int b = g / L, pos = g - b * L;
    const float* xp = X + (size_t)b * D_ * L + pos;
    float acc = 0.f;
#pragma unroll 8
    for (int d = 0; d < D_; ++d) acc += w[d] * xp[(size_t)d * L];
    r[g] = acc;
}

// Wt[f*128+d] = W_res[d*512+f]
__global__ void k_wt(const float* __restrict__ W, float* __restrict__ Wt) {
    int o = blockIdx.x * 256 + threadIdx.x;
    int f = o >> 7, d = o & 127;
    Wt[o] = W[d * 512 + f];
}

// Sdot[b,i,j] = sum_d (w3[d]*C[b,d,i]) * Q[b,d,j]   (64x64 tile, K=128 staged whole)
__global__ __launch_bounds__(256) void k_sdot(const float* __restrict__ C,
        const float* __restrict__ Qm, const float* __restrict__ w3,
        float* __restrict__ Sdot) {
    __shared__ __align__(16) float Cs[D_ * 64];
    __shared__ __align__(16) float Qs[D_ * 64];
    int bid = blockIdx.x;
    int qt = bid & 3, ct = (bid >> 2) & 31, b = bid >> 7;
    int i0 = ct * 64, j0 = qt * 64;
    int tid = threadIdx.x;
    int ii = tid & 63, db = tid >> 6;
#pragma unroll
    for (int k = 0; k < 32; ++k) {
        int dd = db + 4 * k;
        Cs[dd * 64 + ii] = w3[dd] * C[((size_t)b * D_ + dd) * LC_ + i0 + ii];
        Qs[dd * 64 + ii] = Qm[((size_t)b * D_ + dd) * LQ_ + j0 + ii];
    }
    __syncthreads();
    int ti = tid & 15, tj = tid >> 4;
    float acc[4][4] = {};
    for (int dd = 0; dd < D_; ++dd) {
        f4 a = *(const f4*)&Cs[dd * 64 + ti * 4];
        f4 q = *(const f4*)&Qs[dd * 64 + tj * 4];
#pragma unroll
        for (int x = 0; x < 4; ++x)
#pragma unroll
            for (int y = 0; y < 4; ++y)
                acc[x][y] += a[x] * q[y];
    }
#pragma unroll
    for (int x = 0; x < 4; ++x) {
        int i = i0 + ti * 4 + x;
        f4 v = {acc[x][0], acc[x][1], acc[x][2], acc[x][3]};
        *(f4*)&Sdot[((size_t)(b * LC_ + i)) * LQ_ + j0 + tj * 4] = v;
    }
}

// column-softmax partial stats over a 128-row chunk of i (rQ[j] cancels in col softmax)
__global__ __launch_bounds__(256) void k_colstat(const float* __restrict__ Sdot,
        const float* __restrict__ rC, const int* __restrict__ cmask,
        float* __restrict__ pm, float* __restrict__ pz) {
    int b = blockIdx.x >> 4, ch = blockIdx.x & 15;
    int j = threadIdx.x;
    float m = -3.0e38f, z = 0.f;
    for (int k = 0; k < 128; ++k) {
        int i = ch * 128 + k;
        float v = Sdot[((size_t)(b * LC_ + i)) * LQ_ + j] + rC[b * LC_ + i]
                + (cmask[b * LC_ + i] ? 0.f : NEGV);
        float mn = fmaxf(m, v);
        z = z * __expf(m - mn) + __expf(v - mn);
        m = mn;
    }
    pm[blockIdx.x * LQ_ + j] = m;
    pz[blockIdx.x * LQ_ + j] = z;
}

__global__ void k_colcomb(const float* __restrict__ pm, const float* __restrict__ pz,
                          float* __restrict__ mcol, float* __restrict__ zcol) {
    int b = blockIdx.x, j = threadIdx.x;
    float m = -3.0e38f;
#pragma unroll
    for (int c = 0; c < 16; ++c) m = fmaxf(m, pm[(b * 16 + c) * LQ_ + j]);
    float z = 0.f;
#pragma unroll
    for (int c = 0; c < 16; ++c) z += pz[(b * 16 + c) * LQ_ + j] * __expf(pm[(b * 16 + c) * LQ_ + j] - m);
    mcol[b * LQ_ + j] = m;
    zcol[b * LQ_ + j] = z;
}

// part[ks,b,d,j] = sum_{i in ks-range} exp(S - mcol[j]) * Ct[i,d]  (Z folded later)
__global__ __launch_bounds__(256) void k_sctc(const float* __restrict__ Sdot,
        const float* __restrict__ C, const float* __restrict__ rC,
        const int* __restrict__ cmask, const float* __restrict__ mcol,
        float* __restrict__ part) {
    __shared__ __align__(16) float Ps[64 * 68];
    __shared__ __align__(16) float Cs[64 * 68];
    int bid = blockIdx.x;
    int ks = bid & 3, dt = (bid >> 2) & 1, jt = (bid >> 3) & 3, b = bid >> 5;
    int j0 = jt * 64, d0 = dt * 64;
    int tid = threadIdx.x;
    int jj = tid & 63, qb = tid >> 6;
    float mj = mcol[b * LQ_ + j0 + jj];
    int tjq = tid & 15, tdq = tid >> 4;
    float acc[4][4] = {};
    for (int i0 = ks * 512; i0 < ks * 512 + 512; i0 += 64) {
        __syncthreads();
#pragma unroll
        for (int k = 0; k < 16; ++k) {
            int iiw = qb + 4 * k;
            int i = i0 + iiw;
            float v = Sdot[((size_t)(b * LC_ + i)) * LQ_ + j0 + jj] + rC[b * LC_ + i]
                    + (cmask[b * LC_ + i] ? 0.f : NEGV);
            Ps[iiw * 68 + jj] = __expf(v - mj);
            int dd = qb + 4 * k;  // 0..63
            Cs[jj * 68 + dd] = C[((size_t)b * D_ + d0 + dd) * LC_ + i0 + jj];
        }
        __syncthreads();
        for (int iiw = 0; iiw < 64; ++iiw) {
            f4 p = *(const f4*)&Ps[iiw * 68 + tjq * 4];
            f4 cv = *(const f4*)&Cs[iiw * 68 + tdq * 4];
#pragma unroll
            for (int a = 0; a < 4; ++a)
#pragma unroll
                for (int c = 0; c < 4; ++c)
                    acc[a][c] += p[a] * cv[c];
        }
    }
#pragma unroll
    for (int c = 0; c < 4; ++c) {
        int d = d0 + tdq * 4 + c;
        f4 v = {acc[0][c], acc[1][c], acc[2][c], acc[3][c]};
        *(f4*)&part[(((size_t)ks * B_ + b) * D_ + d) * LQ_ + j0 + tjq * 4] = v;
    }
}

__global__ void k_sctc_red(const float* __restrict__ part, const float* __restrict__ zcol,
                           float* __restrict__ ScTCt) {
    int idx = blockIdx.x * 256 + threadIdx.x;  // over B*D*LQ
    float s = 0.f;
#pragma unroll
    for (int ks = 0; ks < 4; ++ks) s += part[(size_t)ks * B_ * D_ * LQ_ + idx];
    int j = idx & (LQ_ - 1);
    int b = idx / (D_ * LQ_);
    ScTCt[idx] = s / zcol[b * LQ_ + j];
}

// per 64-row block: row softmax (rC cancels) then [A|Bm] = P @ [Qt | ScTC]
__global__ __launch_bounds__(256) void k_rowpass(
        const float* __restrict__ Sdot, const float* __restrict__ rQ,
        const int* __restrict__ qmask, const float* __restrict__ Qm,
        const float* __restrict__ ScTCt,
        float* __restrict__ Abuf, float* __restrict__ Bmbuf) {
    __shared__ __align__(16) float Ps[64 * 260];  // [row][j], pad 4
    __shared__ __align__(16) float Ms[256 * 64];  // [col][j-chunk]
    int b = blockIdx.x >> 5, i0 = (blockIdx.x & 31) * 64;
    int tid = threadIdx.x;
    int wv = tid >> 6, lane = tid & 63;
    f4 rq4 = *(const f4*)&rQ[b * LQ_ + lane * 4];
    i4 qm4 = *(const i4*)&qmask[b * LQ_ + lane * 4];
    float base[4];
#pragma unroll
    for (int k = 0; k < 4; ++k) base[k] = rq4[k] + (qm4[k] ? 0.f : NEGV);
    // phase 1: one wave per row, 4 rows in flight, wave-local reductions only
    for (int r16 = 0; r16 < 16; ++r16) {
        int row = r16 * 4 + wv;
        f4 sv = *(const f4*)&Sdot[((size_t)(b * LC_ + i0 + row)) * LQ_ + lane * 4];
        float v[4];
#pragma unroll
        for (int k = 0; k < 4; ++k) v[k] = sv[k] + base[k];
        float m = fmaxf(fmaxf(v[0], v[1]), fmaxf(v[2], v[3]));
#pragma unroll
        for (int s = 32; s > 0; s >>= 1) m = fmaxf(m, __shfl_xor(m, s, 64));
        float e[4], zs = 0.f;
#pragma unroll
        for (int k = 0; k < 4; ++k) { e[k] = __expf(v[k] - m); zs += e[k]; }
#pragma unroll
        for (int s = 32; s > 0; s >>= 1) zs += __shfl_xor(zs, s, 64);
        float rz = 1.f / zs;
        f4 pv = {e[0] * rz, e[1] * rz, e[2] * rz, e[3] * rz};
        *(f4*)&Ps[row * 260 + lane * 4] = pv;
    }
    // phase 2: [A|Bm](64x256) = P(64x256) @ M(256x256)^T-ish, M staged 64 j at a time
    int ti = tid & 15, tc = tid >> 4;
    float acc[4][16] = {};
    for (int jc = 0; jc < 4; ++jc) {
        __syncthreads();
        int jjs = tid & 63, cb = tid >> 6;
        for (int k = 0; k < 64; ++k) {
            int c = cb + 4 * k;  // 0..255; c<128 <=> k<32 (uniform)
            float val = (c < 128)
                ? Qm[((size_t)b * D_ + c) * LQ_ + jc * 64 + jjs]
                : ScTCt[((size_t)b * D_ + (c - 128)) * LQ_ + jc * 64 + jjs];
            Ms[c * 64 + jjs] = val;
        }
        __syncthreads();
        for (int jq = 0; jq < 16; ++jq) {
            float pr[4][4];
#pragma unroll
            for (int rr = 0; rr < 4; ++rr) {
                f4 p = *(const f4*)&Ps[(ti + 16 * rr) * 260 + jc * 64 + jq * 4];
#pragma unroll
                for (int k = 0; k < 4; ++k) pr[rr][k] = p[k];
            }
#pragma unroll
            for (int cc = 0; cc < 16; ++cc) {
                f4 mm = *(const f4*)&Ms[(tc * 16 + cc) * 64 + jq * 4];
#pragma unroll
                for (int rr = 0; rr < 4; ++rr)
#pragma unroll
                    for (int k = 0; k < 4; ++k)
                        acc[rr][cc] += pr[rr][k] * mm[k];
            }
        }
    }
#pragma unroll
    for (int rr = 0; rr < 4; ++rr) {
        int i = i0 + ti + 16 * rr;
#pragma unroll
        for (int cq = 0; cq < 4; ++cq) {
            int c = tc * 16 + cq * 4;
            f4 v = {acc[rr][cq * 4], acc[rr][cq * 4 + 1], acc[rr][cq * 4 + 2], acc[rr][cq * 4 + 3]};
            if (c < 128) *(f4*)&Abuf[((size_t)b * LC_ + i) * D_ + c] = v;
            else         *(f4*)&Bmbuf[((size_t)b * LC_ + i) * D_ + (c - 128)] = v;
        }
    }
}

// out[b,d,i] = relu(b_res[d] + sum_f feat[i,f] * W_res[d,f]); feats from Ct,A,Bm tiles
__global__ __launch_bounds__(256) void k_proj(const float* __restrict__ C,
        const float* __restrict__ Abuf, const float* __restrict__ Bmbuf,
        const float* __restrict__ Wt, const float* __restrict__ bres,
        float* __restrict__ outp) {
    __shared__ __align__(16) float Cts[64 * 132];
    __shared__ __align__(16) float As[64 * 132];
    __shared__ __align__(16) float Bs[64 * 132];
    __shared__ __align__(16) float Ws[64 * 132];
    int b = blockIdx.x >> 5, i0 = (blockIdx.x & 31) * 64;
    int tid = threadIdx.x;
    {
        int ii = tid & 63, dbase = tid >> 6;
#pragma unroll
        for (int k = 0; k < 32; ++k) {
            int dd = dbase + 4 * k;
            Cts[ii * 132 + dd] = C[((size_t)b * D_ + dd) * LC_ + i0 + ii];
        }
    }
    {
        int dd = tid & 127, ibase = tid >> 7;
#pragma unroll
        for (int k = 0; k < 32; ++k) {
            int ii = ibase + 2 * k;
            As[ii * 132 + dd] = Abuf[((size_t)b * LC_ + i0 + ii) * D_ + dd];
            Bs[ii * 132 + dd] = Bmbuf[((size_t)b * LC_ + i0 + ii) * D_ + dd];
        }
    }
    int ti = tid & 15, tc = tid >> 4;
    float br[8];
#pragma unroll
    for (int c = 0; c < 4; ++c) { br[c] = bres[tc * 4 + c]; br[4 + c] = bres[64 + tc * 4 + c]; }
    float acc[4][8] = {};
    for (int fc = 0; fc < 8; ++fc) {
        __syncthreads();
        {
            int dd = tid & 127, fbase = tid >> 7;
#pragma unroll
            for (int k = 0; k < 32; ++k) {
                int ff = fbase + 2 * k;
                Ws[ff * 132 + dd] = Wt[((size_t)(fc * 64 + ff)) * D_ + dd];
            }
        }
        __syncthreads();
        int src = fc >> 1;  // 0:Ct 1:A 2:Ct*A 3:Ct*Bm
        for (int ff = 0; ff < 64; ++ff) {
            int g = (fc & 1) * 64 + ff;
            float F[4];
#pragma unroll
            for (int rr = 0; rr < 4; ++rr) {
                int row = ti + 16 * rr;
                float cv = Cts[row * 132 + g];
                float F_;
                if (src == 0) F_ = cv;
                else if (src == 1) F_ = As[row * 132 + g];
                else if (src == 2) F_ = cv * As[row * 132 + g];
                else F_ = cv * Bs[row * 132 + g];
                F[rr] = F_;
            }
            f4 w0 = *(const f4*)&Ws[ff * 132 + tc * 4];
            f4 w1 = *(const f4*)&Ws[ff * 132 + 64 + tc * 4];
#pragma unroll
            for (int rr = 0; rr < 4; ++rr)
#pragma unroll
                for (int c = 0; c < 4; ++c) {
                    acc[rr][c] += F[rr] * w0[c];
                    acc[rr][4 + c] += F[rr] * w1[c];
                }
        }
    }
#pragma unroll
    for (int rr = 0; rr < 4; ++rr) {
        int i = i0 + ti + 16 * rr;
#pragma unroll
        for (int c = 0; c < 8; ++c) {
            int d = (c < 4) ? (tc * 4 + c) : (64 + tc * 4 + (c - 4));
            float vv = acc[rr][c] + br[c];
            outp[((size_t)b * D_ + d) * LC_ + i] = fmaxf(vv, 0.f);
        }
    }
}

extern "C" void kernel_launch(void* const* d_in, const int* in_sizes, int n_in,
                              void* d_out, int out_size, void* d_ws, size_t ws_size,
                              hipStream_t stream) {
    const float* C = (const float*)d_in[0];
    const float* Q = (const float*)d_in[1];
    const int* cmask = (const int*)d_in[2];
    const int* qmask = (const int*)d_in[3];
    const float* w = (const float*)d_in[4];
    const float* W_res = (const float*)d_in[5];
    const float* b_res = (const float*)d_in[6];
    float* out = (float*)d_out;
    float* ws = (float*)d_ws;

    float* Sdot  = ws;
    float* rC    = Sdot + (size_t)B_ * LC_ * LQ_;
    float* rQ    = rC + B_ * LC_;
    float* pm    = rQ + B_ * LQ_;
    float* pz    = pm + B_ * 16 * LQ_;
    float* mcol  = pz + B_ * 16 * LQ_;
    float* zcol  = mcol + B_ * LQ_;
    float* ScTCt = zcol + B_ * LQ_;
    float* part  = ScTCt + (size_t)B_ * D_ * LQ_;
    float* Abuf  = part + (size_t)4 * B_ * D_ * LQ_;
    float* Bmbuf = Abuf + (size_t)B_ * LC_ * D_;
    float* Wt    = Bmbuf + (size_t)B_ * LC_ * D_;

    k_rvec<<<B_ * LC_ / 256, 256, 0, stream>>>(C, w, rC, LC_);
    k_rvec<<<B_ * LQ_ / 256, 256, 0, stream>>>(Q, w + D_, rQ, LQ_);
    k_wt<<<4 * D_ * D_ / 256, 256, 0, stream>>>(W_res, Wt);
    k_sdot<<<B_ * 32 * 4, 256, 0, stream>>>(C, Q, w + 2 * D_, Sdot);
    k_colstat<<<B_ * 16, 256, 0, stream>>>(Sdot, rC, cmask, pm, pz);
    k_colcomb<<<B_, 256, 0, stream>>>(pm, pz, mcol, zcol);
    k_sctc<<<B_ * 32, 256, 0, stream>>>(Sdot, C, rC, cmask, mcol, part);
    k_sctc_red<<<B_ * D_ * LQ_ / 256, 256, 0, stream>>>(part, zcol, ScTCt);
    k_rowpass<<<B_ * 32, 256, 0, stream>>>(Sdot, rQ, qmask, Q, ScTCt, Abuf, Bmbuf);
    k_proj<<<B_ * 32, 256, 0, stream>>>(C, Abuf, Bmbuf, Wt, b_res, out);
}

// Round 2
// 318.092 us; speedup vs baseline: 2.2360x; 2.2360x over previous
//
#include <hip/hip_runtime.h>

// QANet block. B=16 D=128 LC=2048 LQ=256.
// Round 1: k_proj (431us, 12% VALU, 1 block/CU) -> bf16 MFMA GEMM path
//   k_feat: F[b,i,512] = bf16[Ct, A, Ct*A, Ct*Bm]  (aliases Sdot, dead after rowpass)
//   k_wbf : Wb = bf16(W_res) [d][f] row-major      (aliases part, dead after sctc_red)
//   k_projmm: out(d,i) = relu(W(d,k)*F(k,i) + b)   m97-style, global_load_lds w=16
// ws layout (floats): Sdot 8388608 | rC 32768 | rQ 4096 | pm/pz 65536*2 |
//   mcol/zcol 4096*2 | ScTCt 524288 | part 2097152 | Abuf/Bmbuf 4194304*2 | (Wt slot unused)

#define B_ 16
#define D_ 128
#define LC_ 2048
#define LQ_ 256
#define NEGV -1e30f

typedef float f4 __attribute__((ext_vector_type(4)));
typedef int i4 __attribute__((ext_vector_type(4)));
typedef float f32x4 __attribute__((ext_vector_type(4)));
typedef short bfrag __attribute__((ext_vector_type(8)));
typedef unsigned short ushort_t;

__device__ __forceinline__ unsigned short f2b(float x) {
    unsigned u = __float_as_uint(x);
    u += 0x7fff + ((u >> 16) & 1);
    return (unsigned short)(u >> 16);
}

__device__ __forceinline__ void gld16(const void* g, void* l) {
    __builtin_amdgcn_global_load_lds(
        (const __attribute__((address_space(1))) unsigned*)g,
        (__attribute__((address_space(3))) unsigned*)l, 16, 0, 0);
}

// r[b,pos] = sum_d w[d] * X[b,d,pos]
__global__ void k_rvec(const float* __restrict__ X, const float* __restrict__ w,
                       float* __restrict__ r, int L) {
    int g = blockIdx.x * 256 + threadIdx.x;
    int b = g / L, pos = g - b * L;
    const float* xp = X + (size_t)b * D_ * L + pos;
    float acc = 0.f;
#pragma unroll 8
    for (int d = 0; d < D_; ++d) acc += w[d] * xp[(size_t)d * L];
    r[g] = acc;
}

// Sdot[b,i,j] = sum_d (w3[d]*C[b,d,i]) * Q[b,d,j]
__global__ __launch_bounds__(256) void k_sdot(const float* __restrict__ C,
        const float* __restrict__ Qm, const float* __restrict__ w3,
        float* __restrict__ Sdot) {
    __shared__ __align__(16) float Cs[D_ * 64];
    __shared__ __align__(16) float Qs[D_ * 64];
    int bid = blockIdx.x;
    int qt = bid & 3, ct = (bid >> 2) & 31, b = bid >> 7;
    int i0 = ct * 64, j0 = qt * 64;
    int tid = threadIdx.x;
    int ii = tid & 63, db = tid >> 6;
#pragma unroll
    for (int k = 0; k < 32; ++k) {
        int dd = db + 4 * k;
        Cs[dd * 64 + ii] = w3[dd] * C[((size_t)b * D_ + dd) * LC_ + i0 + ii];
        Qs[dd * 64 + ii] = Qm[((size_t)b * D_ + dd) * LQ_ + j0 + ii];
    }
    __syncthreads();
    int ti = tid & 15, tj = tid >> 4;
    float acc[4][4] = {};
    for (int dd = 0; dd < D_; ++dd) {
        f4 a = *(const f4*)&Cs[dd * 64 + ti * 4];
        f4 q = *(const f4*)&Qs[dd * 64 + tj * 4];
#pragma unroll
        for (int x = 0; x < 4; ++x)
#pragma unroll
            for (int y = 0; y < 4; ++y)
                acc[x][y] += a[x] * q[y];
    }
#pragma unroll
    for (int x = 0; x < 4; ++x) {
        int i = i0 + ti * 4 + x;
        f4 v = {acc[x][0], acc[x][1], acc[x][2], acc[x][3]};
        *(f4*)&Sdot[((size_t)(b * LC_ + i)) * LQ_ + j0 + tj * 4] = v;
    }
}

// column-softmax partial stats over a 128-row chunk of i (rQ[j] cancels)
__global__ __launch_bounds__(256) void k_colstat(const float* __restrict__ Sdot,
        const float* __restrict__ rC, const int* __restrict__ cmask,
        float* __restrict__ pm, float* __restrict__ pz) {
    int b = blockIdx.x >> 4, ch = blockIdx.x & 15;
    int j = threadIdx.x;
    float m = -3.0e38f, z = 0.f;
    for (int k = 0; k < 128; ++k) {
        int i = ch * 128 + k;
        float v = Sdot[((size_t)(b * LC_ + i)) * LQ_ + j] + rC[b * LC_ + i]
                + (cmask[b * LC_ + i] ? 0.f : NEGV);
        float mn = fmaxf(m, v);
        z = z * __expf(m - mn) + __expf(v - mn);
        m = mn;
    }
    pm[blockIdx.x * LQ_ + j] = m;
    pz[blockIdx.x * LQ_ + j] = z;
}

__global__ void k_colcomb(const float* __restrict__ pm, const float* __restrict__ pz,
                          float* __restrict__ mcol, float* __restrict__ zcol) {
    int b = blockIdx.x, j = threadIdx.x;
    float m = -3.0e38f;
#pragma unroll
    for (int c = 0; c < 16; ++c) m = fmaxf(m, pm[(b * 16 + c) * LQ_ + j]);
    float z = 0.f;
#pragma unroll
    for (int c = 0; c < 16; ++c) z += pz[(b * 16 + c) * LQ_ + j] * __expf(pm[(b * 16 + c) * LQ_ + j] - m);
    mcol[b * LQ_ + j] = m;
    zcol[b * LQ_ + j] = z;
}

// part[ks,b,d,j] = sum_{i in ks-range} exp(S - mcol[j]) * Ct[i,d]
__global__ __launch_bounds__(256) void k_sctc(const float* __restrict__ Sdot,
        const float* __restrict__ C, const float* __restrict__ rC,
        const int* __restrict__ cmask, const float* __restrict__ mcol,
        float* __restrict__ part) {
    __shared__ __align__(16) float Ps[64 * 68];
    __shared__ __align__(16) float Cs[64 * 68];
    int bid = blockIdx.x;
    int ks = bid & 3, dt = (bid >> 2) & 1, jt = (bid >> 3) & 3, b = bid >> 5;
    int j0 = jt * 64, d0 = dt * 64;
    int tid = threadIdx.x;
    int jj = tid & 63, qb = tid >> 6;
    float mj = mcol[b * LQ_ + j0 + jj];
    int tjq = tid & 15, tdq = tid >> 4;
    float acc[4][4] = {};
    for (int i0 = ks * 512; i0 < ks * 512 + 512; i0 += 64) {
        __syncthreads();
#pragma unroll
        for (int k = 0; k < 16; ++k) {
            int iiw = qb + 4 * k;
            int i = i0 + iiw;
            float v = Sdot[((size_t)(b * LC_ + i)) * LQ_ + j0 + jj] + rC[b * LC_ + i]
                    + (cmask[b * LC_ + i] ? 0.f : NEGV);
            Ps[iiw * 68 + jj] = __expf(v - mj);
            int dd = qb + 4 * k;
            Cs[jj * 68 + dd] = C[((size_t)b * D_ + d0 + dd) * LC_ + i0 + jj];
        }
        __syncthreads();
        for (int iiw = 0; iiw < 64; ++iiw) {
            f4 p = *(const f4*)&Ps[iiw * 68 + tjq * 4];
            f4 cv = *(const f4*)&Cs[iiw * 68 + tdq * 4];
#pragma unroll
            for (int a = 0; a < 4; ++a)
#pragma unroll
                for (int c = 0; c < 4; ++c)
                    acc[a][c] += p[a] * cv[c];
        }
    }
#pragma unroll
    for (int c = 0; c < 4; ++c) {
        int d = d0 + tdq * 4 + c;
        f4 v = {acc[0][c], acc[1][c], acc[2][c], acc[3][c]};
        *(f4*)&part[(((size_t)ks * B_ + b) * D_ + d) * LQ_ + j0 + tjq * 4] = v;
    }
}

__global__ void k_sctc_red(const float* __restrict__ part, const float* __restrict__ zcol,
                           float* __restrict__ ScTCt) {
    int idx = blockIdx.x * 256 + threadIdx.x;
    float s = 0.f;
#pragma unroll
    for (int ks = 0; ks < 4; ++ks) s += part[(size_t)ks * B_ * D_ * LQ_ + idx];
    int j = idx & (LQ_ - 1);
    int b = idx / (D_ * LQ_);
    ScTCt[idx] = s / zcol[b * LQ_ + j];
}

// per 64-row block: row softmax (rC cancels) then [A|Bm] = P @ [Qt | ScTC]
__global__ __launch_bounds__(256) void k_rowpass(
        const float* __restrict__ Sdot, const float* __restrict__ rQ,
        const int* __restrict__ qmask, const float* __restrict__ Qm,
        const float* __restrict__ ScTCt,
        float* __restrict__ Abuf, float* __restrict__ Bmbuf) {
    __shared__ __align__(16) float Ps[64 * 260];
    __shared__ __align__(16) float Ms[256 * 64];
    int b = blockIdx.x >> 5, i0 = (blockIdx.x & 31) * 64;
    int tid = threadIdx.x;
    int wv = tid >> 6, lane = tid & 63;
    f4 rq4 = *(const f4*)&rQ[b * LQ_ + lane * 4];
    i4 qm4 = *(const i4*)&qmask[b * LQ_ + lane * 4];
    float base[4];
#pragma unroll
    for (int k = 0; k < 4; ++k) base[k] = rq4[k] + (qm4[k] ? 0.f : NEGV);
    for (int r16 = 0; r16 < 16; ++r16) {
        int row = r16 * 4 + wv;
        f4 sv = *(const f4*)&Sdot[((size_t)(b * LC_ + i0 + row)) * LQ_ + lane * 4];
        float v[4];
#pragma unroll
        for (int k = 0; k < 4; ++k) v[k] = sv[k] + base[k];
        float m = fmaxf(fmaxf(v[0], v[1]), fmaxf(v[2], v[3]));
#pragma unroll
        for (int s = 32; s > 0; s >>= 1) m = fmaxf(m, __shfl_xor(m, s, 64));
        float e[4], zs = 0.f;
#pragma unroll
        for (int k = 0; k < 4; ++k) { e[k] = __expf(v[k] - m); zs += e[k]; }
#pragma unroll
        for (int s = 32; s > 0; s >>= 1) zs += __shfl_xor(zs, s, 64);
        float rz = 1.f / zs;
        f4 pv = {e[0] * rz, e[1] * rz, e[2] * rz, e[3] * rz};
        *(f4*)&Ps[row * 260 + lane * 4] = pv;
    }
    int ti = tid & 15, tc = tid >> 4;
    float acc[4][16] = {};
    for (int jc = 0; jc < 4; ++jc) {
        __syncthreads();
        int jjs = tid & 63, cb = tid >> 6;
        for (int k = 0; k < 64; ++k) {
            int c = cb + 4 * k;
            float val = (c < 128)
                ? Qm[((size_t)b * D_ + c) * LQ_ + jc * 64 + jjs]
                : ScTCt[((size_t)b * D_ + (c - 128)) * LQ_ + jc * 64 + jjs];
            Ms[c * 64 + jjs] = val;
        }
        __syncthreads();
        for (int jq = 0; jq < 16; ++jq) {
            float pr[4][4];
#pragma unroll
            for (int rr = 0; rr < 4; ++rr) {
                f4 p = *(const f4*)&Ps[(ti + 16 * rr) * 260 + jc * 64 + jq * 4];
#pragma unroll
                for (int k = 0; k < 4; ++k) pr[rr][k] = p[k];
            }
#pragma unroll
            for (int cc = 0; cc < 16; ++cc) {
                f4 mm = *(const f4*)&Ms[(tc * 16 + cc) * 64 + jq * 4];
#pragma unroll
                for (int rr = 0; rr < 4; ++rr)
#pragma unroll
                    for (int k = 0; k < 4; ++k)
                        acc[rr][cc] += pr[rr][k] * mm[k];
            }
        }
    }
#pragma unroll
    for (int rr = 0; rr < 4; ++rr) {
        int i = i0 + ti + 16 * rr;
#pragma unroll
        for (int cq = 0; cq < 4; ++cq) {
            int c = tc * 16 + cq * 4;
            f4 v = {acc[rr][cq * 4], acc[rr][cq * 4 + 1], acc[rr][cq * 4 + 2], acc[rr][cq * 4 + 3]};
            if (c < 128) *(f4*)&Abuf[((size_t)b * LC_ + i) * D_ + c] = v;
            else         *(f4*)&Bmbuf[((size_t)b * LC_ + i) * D_ + (c - 128)] = v;
        }
    }
}

// Wb = bf16(W_res), layout [d][f] (already row-major for A-operand)
__global__ void k_wbf(const float* __restrict__ W, unsigned short* __restrict__ Wb) {
    int o = blockIdx.x * 256 + threadIdx.x;
    Wb[o] = f2b(W[o]);
}

// F[b,i,512] = bf16[Ct | A | Ct*A | Ct*Bm]
__global__ __launch_bounds__(256) void k_feat(const float* __restrict__ C,
        const float* __restrict__ Abuf, const float* __restrict__ Bmbuf,
        unsigned short* __restrict__ Fb) {
    __shared__ float Cs[64 * 132];
    int b = blockIdx.x >> 5, i0 = (blockIdx.x & 31) * 64;
    int tid = threadIdx.x;
    int ii = tid & 63, db = tid >> 6;
#pragma unroll
    for (int k = 0; k < 32; ++k) {
        int dd = db + 4 * k;
        Cs[ii * 132 + dd] = C[((size_t)b * D_ + dd) * LC_ + i0 + ii];
    }
    __syncthreads();
    int dd = tid & 127, ib = tid >> 7;
    for (int k = 0; k < 32; ++k) {
        int iiw = ib + 2 * k;
        size_t irow = (size_t)b * LC_ + i0 + iiw;
        float ct = Cs[iiw * 132 + dd];
        float a = Abuf[irow * D_ + dd];
        float bm = Bmbuf[irow * D_ + dd];
        size_t fbase = irow * 512;
        Fb[fbase + dd]       = f2b(ct);
        Fb[fbase + 128 + dd] = f2b(a);
        Fb[fbase + 256 + dd] = f2b(ct * a);
        Fb[fbase + 384 + dd] = f2b(ct * bm);
    }
}

// out(d,i) = relu(W(d,k) * F(k,i) + b_res[d]); BM=128 BN=64 BK=64, 4 waves 64x32
__global__ __launch_bounds__(256) void k_projmm(const unsigned short* __restrict__ Wb,
        const unsigned short* __restrict__ Fb, const float* __restrict__ bres,
        float* __restrict__ outp) {
    __shared__ __align__(16) unsigned short Ws[128 * 64];
    __shared__ __align__(16) unsigned short Fs[64 * 64];
    int b = blockIdx.x >> 5, i0 = (blockIdx.x & 31) * 64;
    int tid = threadIdx.x, wv = tid >> 6, lane = tid & 63;
    int wr = wv >> 1, wc = wv & 1;
    int lr = lane >> 3;          // row within 8-row chunk
    int lk = (lane & 7) * 8;     // k element offset (16B granule)
    f32x4 acc[4][2] = {{{0.f, 0.f, 0.f, 0.f}}};
#pragma unroll
    for (int m = 0; m < 4; ++m)
#pragma unroll
        for (int n = 0; n < 2; ++n)
            acc[m][n] = (f32x4){0.f, 0.f, 0.f, 0.f};
    for (int ks = 0; ks < 8; ++ks) {
        int k0 = ks * 64;
        __syncthreads();
        // W tile [128][64]: 16 x 1KB chunks, wave wv -> chunks wv*4..+3
#pragma unroll
        for (int cc = 0; cc < 4; ++cc) {
            int c = wv * 4 + cc;
            gld16(Wb + ((size_t)(c * 8 + lr) * 512 + k0 + lk), &Ws[c * 512]);
        }
        // F tile [64][64]: 8 chunks, wave wv -> chunks wv*2..+1
#pragma unroll
        for (int cc = 0; cc < 2; ++cc) {
            int c = wv * 2 + cc;
            gld16(Fb + ((size_t)(b * LC_ + i0 + c * 8 + lr) * 512 + k0 + lk), &Fs[c * 512]);
        }
        __syncthreads();
#pragma unroll
        for (int kk = 0; kk < 2; ++kk) {
            int ko = kk * 32 + (lane >> 4) * 8;
            bfrag av[4];
#pragma unroll
            for (int m = 0; m < 4; ++m)
                av[m] = *(const bfrag*)&Ws[(wr * 64 + m * 16 + (lane & 15)) * 64 + ko];
#pragma unroll
            for (int n = 0; n < 2; ++n) {
                bfrag bv = *(const bfrag*)&Fs[(wc * 32 + n * 16 + (lane & 15)) * 64 + ko];
#pragma unroll
                for (int m = 0; m < 4; ++m)
                    acc[m][n] = __builtin_amdgcn_mfma_f32_16x16x32_bf16(av[m], bv, acc[m][n], 0, 0, 0);
            }
        }
    }
    int rbase = (lane >> 4) * 4;
#pragma unroll
    for (int m = 0; m < 4; ++m) {
        int dbase = wr * 64 + m * 16 + rbase;
        f4 bias = *(const f4*)&bres[dbase];
#pragma unroll
        for (int n = 0; n < 2; ++n) {
            int i = i0 + wc * 32 + n * 16 + (lane & 15);
#pragma unroll
            for (int r = 0; r < 4; ++r) {
                float v = acc[m][n][r] + bias[r];
                outp[((size_t)(b * D_ + dbase + r)) * LC_ + i] = fmaxf(v, 0.f);
            }
        }
    }
}

extern "C" void kernel_launch(void* const* d_in, const int* in_sizes, int n_in,
                              void* d_out, int out_size, void* d_ws, size_t ws_size,
                              hipStream_t stream) {
    const float* C = (const float*)d_in[0];
    const float* Q = (const float*)d_in[1];
    const int* cmask = (const int*)d_in[2];
    const int* qmask = (const int*)d_in[3];
    const float* w = (const float*)d_in[4];
    const float* W_res = (const float*)d_in[5];
    const float* b_res = (const float*)d_in[6];
    float* out = (float*)d_out;
    float* ws = (float*)d_ws;

    float* Sdot  = ws;
    float* rC    = Sdot + (size_t)B_ * LC_ * LQ_;
    float* rQ    = rC + B_ * LC_;
    float* pm    = rQ + B_ * LQ_;
    float* pz    = pm + B_ * 16 * LQ_;
    float* mcol  = pz + B_ * 16 * LQ_;
    float* zcol  = mcol + B_ * LQ_;
    float* ScTCt = zcol + B_ * LQ_;
    float* part  = ScTCt + (size_t)B_ * D_ * LQ_;
    float* Abuf  = part + (size_t)4 * B_ * D_ * LQ_;
    float* Bmbuf = Abuf + (size_t)B_ * LC_ * D_;
    // aliases (producers dead before consumers write):
    unsigned short* Wb = (unsigned short*)part;  // after k_sctc_red
    unsigned short* Fb = (unsigned short*)Sdot;  // after k_rowpass (exact size match)

    k_rvec<<<B_ * LC_ / 256, 256, 0, stream>>>(C, w, rC, LC_);
    k_rvec<<<B_ * LQ_ / 256, 256, 0, stream>>>(Q, w + D_, rQ, LQ_);
    k_sdot<<<B_ * 32 * 4, 256, 0, stream>>>(C, Q, w + 2 * D_, Sdot);
    k_colstat<<<B_ * 16, 256, 0, stream>>>(Sdot, rC, cmask, pm, pz);
    k_colcomb<<<B_, 256, 0, stream>>>(pm, pz, mcol, zcol);
    k_sctc<<<B_ * 32, 256, 0, stream>>>(Sdot, C, rC, cmask, mcol, part);
    k_sctc_red<<<B_ * D_ * LQ_ / 256, 256, 0, stream>>>(part, zcol, ScTCt);
    k_wbf<<<4 * D_ * D_ / 256, 256, 0, stream>>>(W_res, Wb);
    k_rowpass<<<B_ * 32, 256, 0, stream>>>(Sdot, rQ, qmask, Q, ScTCt, Abuf, Bmbuf);
    k_feat<<<B_ * 32, 256, 0, stream>>>(C, Abuf, Bmbuf, Fb);
    k_projmm<<<B_ * 32, 256, 0, stream>>>(Wb, Fb, b_res, out);
}

// Round 3
// 159.315 us; speedup vs baseline: 4.4645x; 1.9966x over previous
//
#include <hip/hip_runtime.h>

// QANet block. B=16 D=128 LC=2048 LQ=256.
// R1: proj -> bf16 MFMA (k_feat/k_wbf/k_projmm).           711 -> 318 us
// R2: rowpass -> bf16 MFMA fused with feat construction:
//   k_mb: Mb[b][256][256] = bf16[Qt | ScTC]  (aliases Abuf slot)
//   k_rowfused: softmax -> P bf16 in LDS (XOR swizzle) -> MFMA [A|Bm]=P*M
//               -> epilogue writes Fb = bf16[Ct|A|Ct*A|Ct*Bm] directly
//   (k_feat and Abuf/Bmbuf eliminated; Fb aliases Sdot, row-exclusive)

#define B_ 16
#define D_ 128
#define LC_ 2048
#define LQ_ 256
#define NEGV -1e30f

typedef float f4 __attribute__((ext_vector_type(4)));
typedef int i4 __attribute__((ext_vector_type(4)));
typedef float f32x4 __attribute__((ext_vector_type(4)));
typedef short bfrag __attribute__((ext_vector_type(8)));
typedef unsigned short us4 __attribute__((ext_vector_type(4)));

__device__ __forceinline__ unsigned short f2b(float x) {
    unsigned u = __float_as_uint(x);
    u += 0x7fff + ((u >> 16) & 1);
    return (unsigned short)(u >> 16);
}

__device__ __forceinline__ void gld16(const void* g, void* l) {
    __builtin_amdgcn_global_load_lds(
        (const __attribute__((address_space(1))) unsigned*)g,
        (__attribute__((address_space(3))) unsigned*)l, 16, 0, 0);
}

// r[b,pos] = sum_d w[d] * X[b,d,pos]
__global__ void k_rvec(const float* __restrict__ X, const float* __restrict__ w,
                       float* __restrict__ r, int L) {
    int g = blockIdx.x * 256 + threadIdx.x;
    int b = g / L, pos = g - b * L;
    const float* xp = X + (size_t)b * D_ * L + pos;
    float acc = 0.f;
#pragma unroll 8
    for (int d = 0; d < D_; ++d) acc += w[d] * xp[(size_t)d * L];
    r[g] = acc;
}

// Sdot[b,i,j] = sum_d (w3[d]*C[b,d,i]) * Q[b,d,j]
__global__ __launch_bounds__(256) void k_sdot(const float* __restrict__ C,
        const float* __restrict__ Qm, const float* __restrict__ w3,
        float* __restrict__ Sdot) {
    __shared__ __align__(16) float Cs[D_ * 64];
    __shared__ __align__(16) float Qs[D_ * 64];
    int bid = blockIdx.x;
    int qt = bid & 3, ct = (bid >> 2) & 31, b = bid >> 7;
    int i0 = ct * 64, j0 = qt * 64;
    int tid = threadIdx.x;
    int ii = tid & 63, db = tid >> 6;
#pragma unroll
    for (int k = 0; k < 32; ++k) {
        int dd = db + 4 * k;
        Cs[dd * 64 + ii] = w3[dd] * C[((size_t)b * D_ + dd) * LC_ + i0 + ii];
        Qs[dd * 64 + ii] = Qm[((size_t)b * D_ + dd) * LQ_ + j0 + ii];
    }
    __syncthreads();
    int ti = tid & 15, tj = tid >> 4;
    float acc[4][4] = {};
    for (int dd = 0; dd < D_; ++dd) {
        f4 a = *(const f4*)&Cs[dd * 64 + ti * 4];
        f4 q = *(const f4*)&Qs[dd * 64 + tj * 4];
#pragma unroll
        for (int x = 0; x < 4; ++x)
#pragma unroll
            for (int y = 0; y < 4; ++y)
                acc[x][y] += a[x] * q[y];
    }
#pragma unroll
    for (int x = 0; x < 4; ++x) {
        int i = i0 + ti * 4 + x;
        f4 v = {acc[x][0], acc[x][1], acc[x][2], acc[x][3]};
        *(f4*)&Sdot[((size_t)(b * LC_ + i)) * LQ_ + j0 + tj * 4] = v;
    }
}

// column-softmax partial stats over a 128-row chunk of i (rQ[j] cancels)
__global__ __launch_bounds__(256) void k_colstat(const float* __restrict__ Sdot,
        const float* __restrict__ rC, const int* __restrict__ cmask,
        float* __restrict__ pm, float* __restrict__ pz) {
    int b = blockIdx.x >> 4, ch = blockIdx.x & 15;
    int j = threadIdx.x;
    float m = -3.0e38f, z = 0.f;
    for (int k = 0; k < 128; ++k) {
        int i = ch * 128 + k;
        float v = Sdot[((size_t)(b * LC_ + i)) * LQ_ + j] + rC[b * LC_ + i]
                + (cmask[b * LC_ + i] ? 0.f : NEGV);
        float mn = fmaxf(m, v);
        z = z * __expf(m - mn) + __expf(v - mn);
        m = mn;
    }
    pm[blockIdx.x * LQ_ + j] = m;
    pz[blockIdx.x * LQ_ + j] = z;
}

__global__ void k_colcomb(const float* __restrict__ pm, const float* __restrict__ pz,
                          float* __restrict__ mcol, float* __restrict__ zcol) {
    int b = blockIdx.x, j = threadIdx.x;
    float m = -3.0e38f;
#pragma unroll
    for (int c = 0; c < 16; ++c) m = fmaxf(m, pm[(b * 16 + c) * LQ_ + j]);
    float z = 0.f;
#pragma unroll
    for (int c = 0; c < 16; ++c) z += pz[(b * 16 + c) * LQ_ + j] * __expf(pm[(b * 16 + c) * LQ_ + j] - m);
    mcol[b * LQ_ + j] = m;
    zcol[b * LQ_ + j] = z;
}

// part[ks,b,d,j] = sum_{i in ks-range} exp(S - mcol[j]) * Ct[i,d]
__global__ __launch_bounds__(256) void k_sctc(const float* __restrict__ Sdot,
        const float* __restrict__ C, const float* __restrict__ rC,
        const int* __restrict__ cmask, const float* __restrict__ mcol,
        float* __restrict__ part) {
    __shared__ __align__(16) float Ps[64 * 68];
    __shared__ __align__(16) float Cs[64 * 68];
    int bid = blockIdx.x;
    int ks = bid & 3, dt = (bid >> 2) & 1, jt = (bid >> 3) & 3, b = bid >> 5;
    int j0 = jt * 64, d0 = dt * 64;
    int tid = threadIdx.x;
    int jj = tid & 63, qb = tid >> 6;
    float mj = mcol[b * LQ_ + j0 + jj];
    int tjq = tid & 15, tdq = tid >> 4;
    float acc[4][4] = {};
    for (int i0 = ks * 512; i0 < ks * 512 + 512; i0 += 64) {
        __syncthreads();
#pragma unroll
        for (int k = 0; k < 16; ++k) {
            int iiw = qb + 4 * k;
            int i = i0 + iiw;
            float v = Sdot[((size_t)(b * LC_ + i)) * LQ_ + j0 + jj] + rC[b * LC_ + i]
                    + (cmask[b * LC_ + i] ? 0.f : NEGV);
            Ps[iiw * 68 + jj] = __expf(v - mj);
            int dd = qb + 4 * k;
            Cs[jj * 68 + dd] = C[((size_t)b * D_ + d0 + dd) * LC_ + i0 + jj];
        }
        __syncthreads();
        for (int iiw = 0; iiw < 64; ++iiw) {
            f4 p = *(const f4*)&Ps[iiw * 68 + tjq * 4];
            f4 cv = *(const f4*)&Cs[iiw * 68 + tdq * 4];
#pragma unroll
            for (int a = 0; a < 4; ++a)
#pragma unroll
                for (int c = 0; c < 4; ++c)
                    acc[a][c] += p[a] * cv[c];
        }
    }
#pragma unroll
    for (int c = 0; c < 4; ++c) {
        int d = d0 + tdq * 4 + c;
        f4 v = {acc[0][c], acc[1][c], acc[2][c], acc[3][c]};
        *(f4*)&part[(((size_t)ks * B_ + b) * D_ + d) * LQ_ + j0 + tjq * 4] = v;
    }
}

__global__ void k_sctc_red(const float* __restrict__ part, const float* __restrict__ zcol,
                           float* __restrict__ ScTCt) {
    int idx = blockIdx.x * 256 + threadIdx.x;
    float s = 0.f;
#pragma unroll
    for (int ks = 0; ks < 4; ++ks) s += part[(size_t)ks * B_ * D_ * LQ_ + idx];
    int j = idx & (LQ_ - 1);
    int b = idx / (D_ * LQ_);
    ScTCt[idx] = s / zcol[b * LQ_ + j];
}

// Mb[b][c][j] = bf16( c<128 ? Qt[j,c] : ScTC[j,c-128] )  (row c, j contiguous)
__global__ void k_mb(const float* __restrict__ Qm, const float* __restrict__ ScTCt,
                     unsigned short* __restrict__ Mb) {
    int o = blockIdx.x * 256 + threadIdx.x;
    int j = o & 255, c = (o >> 8) & 255, b = o >> 16;
    float v = (c < 128) ? Qm[((size_t)b * D_ + c) * LQ_ + j]
                        : ScTCt[((size_t)b * D_ + (c - 128)) * LQ_ + j];
    Mb[o] = f2b(v);
}

// Wb = bf16(W_res), layout [d][f]
__global__ void k_wbf(const float* __restrict__ W, unsigned short* __restrict__ Wb) {
    int o = blockIdx.x * 256 + threadIdx.x;
    Wb[o] = f2b(W[o]);
}

// Fused: row softmax -> [A|Bm] = P @ M (MFMA bf16) -> Fb = bf16[Ct|A|Ct*A|Ct*Bm]
__global__ __launch_bounds__(256) void k_rowfused(
        const float* __restrict__ Sdot, const float* __restrict__ rQ,
        const int* __restrict__ qmask, const unsigned short* __restrict__ Mb,
        const float* __restrict__ C, unsigned short* __restrict__ Fb) {
    __shared__ __align__(16) unsigned short Ps[64 * 256];  // 32 KB, XOR-swizzled
    __shared__ __align__(16) unsigned short Ms[256 * 64];  // 32 KB chunk / reused as Cts
    int b = blockIdx.x >> 5, i0 = (blockIdx.x & 31) * 64;
    int tid = threadIdx.x, wv = tid >> 6, lane = tid & 63;

    // ---- phase 1: softmax, P -> bf16 LDS (granule swizzle g ^= row&7) ----
    f4 rq4 = *(const f4*)&rQ[b * LQ_ + lane * 4];
    i4 qm4 = *(const i4*)&qmask[b * LQ_ + lane * 4];
    float base[4];
#pragma unroll
    for (int k = 0; k < 4; ++k) base[k] = rq4[k] + (qm4[k] ? 0.f : NEGV);
    for (int r16 = 0; r16 < 16; ++r16) {
        int row = r16 * 4 + wv;
        f4 sv = *(const f4*)&Sdot[((size_t)(b * LC_ + i0 + row)) * LQ_ + lane * 4];
        float v[4];
#pragma unroll
        for (int k = 0; k < 4; ++k) v[k] = sv[k] + base[k];
        float m = fmaxf(fmaxf(v[0], v[1]), fmaxf(v[2], v[3]));
#pragma unroll
        for (int s = 32; s > 0; s >>= 1) m = fmaxf(m, __shfl_xor(m, s, 64));
        float e[4], zs = 0.f;
#pragma unroll
        for (int k = 0; k < 4; ++k) { e[k] = __expf(v[k] - m); zs += e[k]; }
#pragma unroll
        for (int s = 32; s > 0; s >>= 1) zs += __shfl_xor(zs, s, 64);
        float rz = 1.f / zs;
        us4 pk;
#pragma unroll
        for (int k = 0; k < 4; ++k) pk[k] = f2b(e[k] * rz);
        int g = (lane >> 1) ^ (row & 7);
        *(us4*)((char*)Ps + row * 512 + (g << 4) + (lane & 1) * 8) = pk;
    }

    // ---- phase 2: [A|Bm](64x256) = P(64x256) @ M(256 c x 256 j), K-chunks of 64 j ----
    int r8 = lane >> 3, g8 = lane & 7;
    f32x4 acc[4][4];
#pragma unroll
    for (int m = 0; m < 4; ++m)
#pragma unroll
        for (int n = 0; n < 4; ++n) acc[m][n] = (f32x4){0.f, 0.f, 0.f, 0.f};
    for (int jc = 0; jc < 4; ++jc) {
        __syncthreads();
        // stage Ms[c][64 j] (128 B rows, 8 granules), pre-swizzled source
#pragma unroll
        for (int t = 0; t < 8; ++t) {
            int cb = wv * 64 + t * 8;
            int c = cb + r8;
            int gs = g8 ^ (c & 7);
            gld16(Mb + ((size_t)(b * 256 + c)) * LQ_ + jc * 64 + gs * 8, &Ms[cb * 64]);
        }
        __syncthreads();
#pragma unroll
        for (int kk = 0; kk < 2; ++kk) {
            bfrag av[4];
#pragma unroll
            for (int m = 0; m < 4; ++m) {
                int row = m * 16 + (lane & 15);
                int gp = (jc * 8 + kk * 4 + (lane >> 4)) ^ (row & 7);
                av[m] = *(const bfrag*)((const char*)Ps + row * 512 + (gp << 4));
            }
#pragma unroll
            for (int n = 0; n < 4; ++n) {
                int c = wv * 64 + n * 16 + (lane & 15);
                int gb = (kk * 4 + (lane >> 4)) ^ (c & 7);
                bfrag bv = *(const bfrag*)((const char*)Ms + c * 128 + (gb << 4));
#pragma unroll
                for (int m = 0; m < 4; ++m)
                    acc[m][n] = __builtin_amdgcn_mfma_f32_16x16x32_bf16(av[m], bv, acc[m][n], 0, 0, 0);
            }
        }
    }

    // ---- epilogue: restage Ct tile (fp32, swizzled) then write feats ----
    __syncthreads();
    float* Cts = (float*)Ms;  // [128 d][64 i], 256 B rows, 16 granules
    int r4 = lane >> 4, g16 = lane & 15;
#pragma unroll
    for (int t = 0; t < 8; ++t) {
        int db = wv * 32 + t * 4;
        int d = db + r4;
        int gs = g16 ^ (d & 7);
        gld16(C + ((size_t)(b * D_ + d)) * LC_ + i0 + gs * 4, (char*)Cts + db * 256);
    }
    __syncthreads();
    size_t rowb = (size_t)b * LC_ + i0;
    bool isA = (wv < 2);
    int dbase = (wv & 1) * 64;
#pragma unroll
    for (int m = 0; m < 4; ++m) {
        int irow = m * 16 + r4 * 4;
#pragma unroll
        for (int n = 0; n < 4; ++n) {
            int d = dbase + n * 16 + (lane & 15);
            int gc = (m * 4 + r4) ^ (d & 7);
            f4 ct = *(const f4*)((const char*)Cts + d * 256 + (gc << 4));
            f32x4 av = acc[m][n];
            if (isA) {
#pragma unroll
                for (int r = 0; r < 4; ++r) {
                    size_t fb = (rowb + irow + r) * 512;
                    Fb[fb + 128 + d] = f2b(av[r]);
                    Fb[fb + 256 + d] = f2b(ct[r] * av[r]);
                }
            } else {
#pragma unroll
                for (int r = 0; r < 4; ++r) {
                    size_t fb = (rowb + irow + r) * 512;
                    Fb[fb + d]       = f2b(ct[r]);
                    Fb[fb + 384 + d] = f2b(ct[r] * av[r]);
                }
            }
        }
    }
}

// out(d,i) = relu(W(d,k) * F(k,i) + b_res[d]); BM=128 BN=64 BK=64, 4 waves 64x32
__global__ __launch_bounds__(256) void k_projmm(const unsigned short* __restrict__ Wb,
        const unsigned short* __restrict__ Fb, const float* __restrict__ bres,
        float* __restrict__ outp) {
    __shared__ __align__(16) unsigned short Ws[128 * 64];
    __shared__ __align__(16) unsigned short Fs[64 * 64];
    int b = blockIdx.x >> 5, i0 = (blockIdx.x & 31) * 64;
    int tid = threadIdx.x, wv = tid >> 6, lane = tid & 63;
    int wr = wv >> 1, wc = wv & 1;
    int lr = lane >> 3;
    int lk = (lane & 7) * 8;
    f32x4 acc[4][2];
#pragma unroll
    for (int m = 0; m < 4; ++m)
#pragma unroll
        for (int n = 0; n < 2; ++n)
            acc[m][n] = (f32x4){0.f, 0.f, 0.f, 0.f};
    for (int ks = 0; ks < 8; ++ks) {
        int k0 = ks * 64;
        __syncthreads();
#pragma unroll
        for (int cc = 0; cc < 4; ++cc) {
            int c = wv * 4 + cc;
            gld16(Wb + ((size_t)(c * 8 + lr) * 512 + k0 + lk), &Ws[c * 512]);
        }
#pragma unroll
        for (int cc = 0; cc < 2; ++cc) {
            int c = wv * 2 + cc;
            gld16(Fb + ((size_t)(b * LC_ + i0 + c * 8 + lr) * 512 + k0 + lk), &Fs[c * 512]);
        }
        __syncthreads();
#pragma unroll
        for (int kk = 0; kk < 2; ++kk) {
            int ko = kk * 32 + (lane >> 4) * 8;
            bfrag av[4];
#pragma unroll
            for (int m = 0; m < 4; ++m)
                av[m] = *(const bfrag*)&Ws[(wr * 64 + m * 16 + (lane & 15)) * 64 + ko];
#pragma unroll
            for (int n = 0; n < 2; ++n) {
                bfrag bv = *(const bfrag*)&Fs[(wc * 32 + n * 16 + (lane & 15)) * 64 + ko];
#pragma unroll
                for (int m = 0; m < 4; ++m)
                    acc[m][n] = __builtin_amdgcn_mfma_f32_16x16x32_bf16(av[m], bv, acc[m][n], 0, 0, 0);
            }
        }
    }
    int rbase = (lane >> 4) * 4;
#pragma unroll
    for (int m = 0; m < 4; ++m) {
        int dbase = wr * 64 + m * 16 + rbase;
        f4 bias = *(const f4*)&bres[dbase];
#pragma unroll
        for (int n = 0; n < 2; ++n) {
            int i = i0 + wc * 32 + n * 16 + (lane & 15);
#pragma unroll
            for (int r = 0; r < 4; ++r) {
                float v = acc[m][n][r] + bias[r];
                outp[((size_t)(b * D_ + dbase + r)) * LC_ + i] = fmaxf(v, 0.f);
            }
        }
    }
}

extern "C" void kernel_launch(void* const* d_in, const int* in_sizes, int n_in,
                              void* d_out, int out_size, void* d_ws, size_t ws_size,
                              hipStream_t stream) {
    const float* C = (const float*)d_in[0];
    const float* Q = (const float*)d_in[1];
    const int* cmask = (const int*)d_in[2];
    const int* qmask = (const int*)d_in[3];
    const float* w = (const float*)d_in[4];
    const float* W_res = (const float*)d_in[5];
    const float* b_res = (const float*)d_in[6];
    float* out = (float*)d_out;
    float* ws = (float*)d_ws;

    float* Sdot  = ws;
    float* rC    = Sdot + (size_t)B_ * LC_ * LQ_;
    float* rQ    = rC + B_ * LC_;
    float* pm    = rQ + B_ * LQ_;
    float* pz    = pm + B_ * 16 * LQ_;
    float* mcol  = pz + B_ * 16 * LQ_;
    float* zcol  = mcol + B_ * LQ_;
    float* ScTCt = zcol + B_ * LQ_;
    float* part  = ScTCt + (size_t)B_ * D_ * LQ_;
    float* Abuf  = part + (size_t)4 * B_ * D_ * LQ_;   // slot reused for Mb
    // aliases (producers dead before consumers write):
    unsigned short* Wb = (unsigned short*)part;   // after k_sctc_red
    unsigned short* Fb = (unsigned short*)Sdot;   // rowfused reads row then writes row
    unsigned short* Mb = (unsigned short*)Abuf;   // after k_sctc_red (needs ScTCt)

    k_rvec<<<B_ * LC_ / 256, 256, 0, stream>>>(C, w, rC, LC_);
    k_rvec<<<B_ * LQ_ / 256, 256, 0, stream>>>(Q, w + D_, rQ, LQ_);
    k_sdot<<<B_ * 32 * 4, 256, 0, stream>>>(C, Q, w + 2 * D_, Sdot);
    k_colstat<<<B_ * 16, 256, 0, stream>>>(Sdot, rC, cmask, pm, pz);
    k_colcomb<<<B_, 256, 0, stream>>>(pm, pz, mcol, zcol);
    k_sctc<<<B_ * 32, 256, 0, stream>>>(Sdot, C, rC, cmask, mcol, part);
    k_sctc_red<<<B_ * D_ * LQ_ / 256, 256, 0, stream>>>(part, zcol, ScTCt);
    k_mb<<<B_ * 256 * LQ_ / 256, 256, 0, stream>>>(Q, ScTCt, Mb);
    k_wbf<<<4 * D_ * D_ / 256, 256, 0, stream>>>(W_res, Wb);
    k_rowfused<<<B_ * 32, 256, 0, stream>>>(Sdot, rQ, qmask, Mb, C, Fb);
    k_projmm<<<B_ * 32, 256, 0, stream>>>(Wb, Fb, b_res, out);
}

// Round 5
// 158.637 us; speedup vs baseline: 4.4836x; 1.0043x over previous
//
#include <hip/hip_runtime.h>

// QANet block. B=16 D=128 LC=2048 LQ=256.
// R1: proj -> bf16 MFMA.                         711 -> 318 us
// R2: rowpass -> fused bf16 MFMA.                318 -> 159 us
// R3: column path -> MFMA + bf16, no max-pass.   FAILED (absmax 2.3e28, garbage-bits class)
// R4: same structure, k_sctcmm de-risked to proven constructs only:
//     - A-fragment pack via f2b element stores (no cvt_pk asm, no union)
//     - Cbf staging via reg load + plain ds_write_b128 XOR-granule (no gld16)

#define B_ 16
#define D_ 128
#define LC_ 2048
#define LQ_ 256
#define NEGV -1e30f

typedef float f4 __attribute__((ext_vector_type(4)));
typedef int i4 __attribute__((ext_vector_type(4)));
typedef float f32x4 __attribute__((ext_vector_type(4)));
typedef short bfrag __attribute__((ext_vector_type(8)));
typedef unsigned short us4 __attribute__((ext_vector_type(4)));

__device__ __forceinline__ unsigned short f2b(float x) {
    unsigned u = __float_as_uint(x);
    u += 0x7fff + ((u >> 16) & 1);
    return (unsigned short)(u >> 16);
}

__device__ __forceinline__ float b2f(short s) {
    return __uint_as_float(((unsigned)(unsigned short)s) << 16);
}

__device__ __forceinline__ void gld16(const void* g, void* l) {
    __builtin_amdgcn_global_load_lds(
        (const __attribute__((address_space(1))) unsigned*)g,
        (__attribute__((address_space(3))) unsigned*)l, 16, 0, 0);
}

// r[b,pos] = sum_d w[d] * X[b,d,pos] + (mask ? 0 : NEG)
__global__ void k_rvec(const float* __restrict__ X, const float* __restrict__ w,
                       const int* __restrict__ mask, float* __restrict__ r, int L) {
    int g = blockIdx.x * 256 + threadIdx.x;
    int b = g / L, pos = g - b * L;
    const float* xp = X + (size_t)b * D_ * L + pos;
    float acc = 0.f;
#pragma unroll 8
    for (int d = 0; d < D_; ++d) acc += w[d] * xp[(size_t)d * L];
    r[g] = acc + (mask[g] ? 0.f : NEGV);
}

// Sdot fp32 [b][i][j]; SdotT bf16 [b][j][i]; Cbf bf16 [b][d][i]
__global__ __launch_bounds__(256) void k_sdot(const float* __restrict__ C,
        const float* __restrict__ Qm, const float* __restrict__ w3,
        float* __restrict__ Sdot, unsigned short* __restrict__ SdotT,
        unsigned short* __restrict__ Cbf) {
    __shared__ __align__(16) float Cs[D_ * 64];
    __shared__ __align__(16) float Qs[D_ * 64];
    int bid = blockIdx.x;
    int qt = bid & 3, ct = (bid >> 2) & 31, b = bid >> 7;
    int i0 = ct * 64, j0 = qt * 64;
    int tid = threadIdx.x;
    int ii = tid & 63, db = tid >> 6;
#pragma unroll
    for (int k = 0; k < 32; ++k) {
        int dd = db + 4 * k;
        float raw = C[((size_t)b * D_ + dd) * LC_ + i0 + ii];
        Cs[dd * 64 + ii] = w3[dd] * raw;
        Qs[dd * 64 + ii] = Qm[((size_t)b * D_ + dd) * LQ_ + j0 + ii];
        if (qt == 0) Cbf[((size_t)b * D_ + dd) * LC_ + i0 + ii] = f2b(raw);
    }
    __syncthreads();
    int ti = tid & 15, tj = tid >> 4;
    float acc[4][4] = {};
    for (int dd = 0; dd < D_; ++dd) {
        f4 a = *(const f4*)&Cs[dd * 64 + ti * 4];
        f4 q = *(const f4*)&Qs[dd * 64 + tj * 4];
#pragma unroll
        for (int x = 0; x < 4; ++x)
#pragma unroll
            for (int y = 0; y < 4; ++y)
                acc[x][y] += a[x] * q[y];
    }
#pragma unroll
    for (int x = 0; x < 4; ++x) {
        int i = i0 + ti * 4 + x;
        f4 v = {acc[x][0], acc[x][1], acc[x][2], acc[x][3]};
        *(f4*)&Sdot[((size_t)(b * LC_ + i)) * LQ_ + j0 + tj * 4] = v;
    }
#pragma unroll
    for (int y = 0; y < 4; ++y) {
        int j = j0 + tj * 4 + y;
        us4 pk = {f2b(acc[0][y]), f2b(acc[1][y]), f2b(acc[2][y]), f2b(acc[3][y])};
        *(us4*)&SdotT[((size_t)(b * LQ_ + j)) * LC_ + i0 + ti * 4] = pk;
    }
}

// zcol[b,j] = sum_i exp(SdotT[b,j,i] + rcm[b,i])  (no max shift; masked -> exp->0)
__global__ __launch_bounds__(256) void k_zcol(const unsigned short* __restrict__ SdotT,
        const float* __restrict__ rcm, float* __restrict__ zcol) {
    int b = blockIdx.x >> 6, j4 = blockIdx.x & 63;
    int wv = threadIdx.x >> 6, lane = threadIdx.x & 63;
    int j = j4 * 4 + wv;
    const unsigned short* row = SdotT + ((size_t)(b * LQ_ + j)) * LC_;
    const float* rc = rcm + b * LC_;
    float z = 0.f;
#pragma unroll
    for (int it = 0; it < 4; ++it) {
        int i = it * 512 + lane * 8;
        bfrag sd = *(const bfrag*)&row[i];
        f4 r0 = *(const f4*)&rc[i];
        f4 r1 = *(const f4*)&rc[i + 4];
#pragma unroll
        for (int e = 0; e < 8; ++e) {
            float f = b2f(sd[e]) + (e < 4 ? r0[e] : r1[e - 4]);
            z += __expf(f);
        }
    }
#pragma unroll
    for (int s = 32; s > 0; s >>= 1) z += __shfl_xor(z, s, 64);
    if (lane == 0) zcol[b * LQ_ + j] = z;
}

// part[ks][b][j][d] = sum_{i in ks*512..} exp(SdotT+rcm) * Cbf[d][i]
// block: 64j x 128d, 4 waves (jw -> 32j, dw -> 64d), chunks of 64 i
__global__ __launch_bounds__(256) void k_sctcmm(
        const unsigned short* __restrict__ SdotT, const float* __restrict__ rcm,
        const unsigned short* __restrict__ Cbf, float* __restrict__ part) {
    __shared__ __align__(16) unsigned short Cs[128 * 64];  // 16 KB, XOR-granule
    int bid = blockIdx.x;
    int ks = bid & 3, jt = (bid >> 2) & 3, b = bid >> 4;
    int j0 = jt * 64;
    int tid = threadIdx.x, wv = tid >> 6, lane = tid & 63;
    int jw = wv & 1, dw = wv >> 1;
    int l15 = lane & 15, l4 = lane >> 4;
    size_t sdbase0 = ((size_t)(b * LQ_ + j0 + jw * 32 + l15)) * LC_;
    size_t sdbase1 = sdbase0 + (size_t)16 * LC_;
    f32x4 acc[2][4];
#pragma unroll
    for (int mm = 0; mm < 2; ++mm)
#pragma unroll
        for (int nn = 0; nn < 4; ++nn) acc[mm][nn] = (f32x4){0.f, 0.f, 0.f, 0.f};
    for (int c = 0; c < 8; ++c) {
        int ic = ks * 512 + c * 64;
        // stage-load Cbf chunk to registers (overlaps previous MFMA phase)
        bfrag stg[4];
        int rr[4], gg[4];
#pragma unroll
        for (int t = 0; t < 4; ++t) {
            int gi = t * 256 + tid;          // granule 0..1023
            rr[t] = gi >> 3;                 // row d 0..127
            gg[t] = gi & 7;                  // granule-in-row
            stg[t] = *(const bfrag*)&Cbf[((size_t)(b * D_ + rr[t])) * LC_ + ic + gg[t] * 8];
        }
        // A fragments: exp in registers (proven f2b path, no asm)
        bfrag afr[2][2];
#pragma unroll
        for (int kk = 0; kk < 2; ++kk) {
            int ib = ic + kk * 32 + l4 * 8;
            f4 r0 = *(const f4*)&rcm[b * LC_ + ib];
            f4 r1 = *(const f4*)&rcm[b * LC_ + ib + 4];
#pragma unroll
            for (int mm = 0; mm < 2; ++mm) {
                bfrag sd = *(const bfrag*)&SdotT[(mm ? sdbase1 : sdbase0) + ib];
                bfrag fr;
#pragma unroll
                for (int e = 0; e < 8; ++e)
                    fr[e] = (short)f2b(__expf(b2f(sd[e]) + (e < 4 ? r0[e] : r1[e - 4])));
                afr[mm][kk] = fr;
            }
        }
        __syncthreads();  // all waves done MFMA-reading previous Cs
#pragma unroll
        for (int t = 0; t < 4; ++t)
            *(bfrag*)&Cs[rr[t] * 64 + ((gg[t] ^ (rr[t] & 7)) << 3)] = stg[t];
        __syncthreads();  // Cs(c) visible
#pragma unroll
        for (int kk = 0; kk < 2; ++kk)
#pragma unroll
            for (int nn = 0; nn < 4; ++nn) {
                int d = dw * 64 + nn * 16 + l15;
                int g = kk * 4 + l4;
                bfrag bv = *(const bfrag*)&Cs[d * 64 + ((g ^ (d & 7)) << 3)];
#pragma unroll
                for (int mm = 0; mm < 2; ++mm)
                    acc[mm][nn] = __builtin_amdgcn_mfma_f32_16x16x32_bf16(afr[mm][kk], bv, acc[mm][nn], 0, 0, 0);
            }
    }
#pragma unroll
    for (int mm = 0; mm < 2; ++mm)
#pragma unroll
        for (int nn = 0; nn < 4; ++nn) {
            int d = dw * 64 + nn * 16 + l15;
#pragma unroll
            for (int r = 0; r < 4; ++r) {
                int j = j0 + jw * 32 + mm * 16 + l4 * 4 + r;
                part[((size_t)(ks * B_ + b) * LQ_ + j) * D_ + d] = acc[mm][nn][r];
            }
        }
}

// Mb[b][128+d][j] = bf16( sum_ks part[ks][b][j][d] / zcol[b][j] )  via LDS transpose
__global__ __launch_bounds__(256) void k_red(const float* __restrict__ part,
        const float* __restrict__ zcol, unsigned short* __restrict__ Mb) {
    __shared__ float Ts[64][68];
    int bid = blockIdx.x;  // 16 * 4 * 2
    int dt = bid & 1, jt = (bid >> 1) & 3, b = bid >> 3;
    int j0 = jt * 64, d0 = dt * 64;
    int tid = threadIdx.x;
    {
        int jj = tid >> 2, dq = (tid & 3) * 16;
        float rz = 1.0f / zcol[b * LQ_ + j0 + jj];
        f4 s[4];
#pragma unroll
        for (int q = 0; q < 4; ++q) s[q] = (f4){0.f, 0.f, 0.f, 0.f};
#pragma unroll
        for (int ks = 0; ks < 4; ++ks) {
            size_t base = ((size_t)(ks * B_ + b) * LQ_ + j0 + jj) * D_ + d0 + dq;
#pragma unroll
            for (int q = 0; q < 4; ++q) {
                f4 v = *(const f4*)&part[base + q * 4];
                s[q] += v;
            }
        }
#pragma unroll
        for (int q = 0; q < 4; ++q) {
            f4 v = {s[q][0] * rz, s[q][1] * rz, s[q][2] * rz, s[q][3] * rz};
            *(f4*)&Ts[jj][dq + q * 4] = v;
        }
    }
    __syncthreads();
    {
        int dd = tid >> 2, jq = (tid & 3) * 16;
        us4 o0, o1, o2, o3;
#pragma unroll
        for (int q = 0; q < 4; ++q) o0[q] = f2b(Ts[jq + q][dd]);
#pragma unroll
        for (int q = 0; q < 4; ++q) o1[q] = f2b(Ts[jq + 4 + q][dd]);
#pragma unroll
        for (int q = 0; q < 4; ++q) o2[q] = f2b(Ts[jq + 8 + q][dd]);
#pragma unroll
        for (int q = 0; q < 4; ++q) o3[q] = f2b(Ts[jq + 12 + q][dd]);
        unsigned short* dst = Mb + ((size_t)(b * 256 + 128 + d0 + dd)) * LQ_ + j0 + jq;
        *(us4*)&dst[0] = o0; *(us4*)&dst[4] = o1; *(us4*)&dst[8] = o2; *(us4*)&dst[12] = o3;
    }
}

// Mb rows 0..127: bf16 Qt  (c-major, j contiguous)
__global__ void k_mb(const float* __restrict__ Qm, unsigned short* __restrict__ Mb) {
    int o = blockIdx.x * 256 + threadIdx.x;
    int j = o & 255, c = (o >> 8) & 127, b = o >> 15;
    Mb[((size_t)(b * 256 + c)) * LQ_ + j] = f2b(Qm[((size_t)b * D_ + c) * LQ_ + j]);
}

// Wb = bf16(W_res), layout [d][f]
__global__ void k_wbf(const float* __restrict__ W, unsigned short* __restrict__ Wb) {
    int o = blockIdx.x * 256 + threadIdx.x;
    Wb[o] = f2b(W[o]);
}

// Fused: row softmax -> [A|Bm] = P @ M (MFMA bf16) -> Fb = bf16[Ct|A|Ct*A|Ct*Bm]
__global__ __launch_bounds__(256) void k_rowfused(
        const float* __restrict__ Sdot, const float* __restrict__ rQm,
        const unsigned short* __restrict__ Mb,
        const float* __restrict__ C, unsigned short* __restrict__ Fb) {
    __shared__ __align__(16) unsigned short Ps[64 * 256];
    __shared__ __align__(16) unsigned short Ms[256 * 64];
    int b = blockIdx.x >> 5, i0 = (blockIdx.x & 31) * 64;
    int tid = threadIdx.x, wv = tid >> 6, lane = tid & 63;

    f4 base = *(const f4*)&rQm[b * LQ_ + lane * 4];  // mask pre-folded
    for (int r16 = 0; r16 < 16; ++r16) {
        int row = r16 * 4 + wv;
        f4 sv = *(const f4*)&Sdot[((size_t)(b * LC_ + i0 + row)) * LQ_ + lane * 4];
        float v[4];
#pragma unroll
        for (int k = 0; k < 4; ++k) v[k] = sv[k] + base[k];
        float m = fmaxf(fmaxf(v[0], v[1]), fmaxf(v[2], v[3]));
#pragma unroll
        for (int s = 32; s > 0; s >>= 1) m = fmaxf(m, __shfl_xor(m, s, 64));
        float e[4], zs = 0.f;
#pragma unroll
        for (int k = 0; k < 4; ++k) { e[k] = __expf(v[k] - m); zs += e[k]; }
#pragma unroll
        for (int s = 32; s > 0; s >>= 1) zs += __shfl_xor(zs, s, 64);
        float rz = 1.f / zs;
        us4 pk;
#pragma unroll
        for (int k = 0; k < 4; ++k) pk[k] = f2b(e[k] * rz);
        int g = (lane >> 1) ^ (row & 7);
        *(us4*)((char*)Ps + row * 512 + (g << 4) + (lane & 1) * 8) = pk;
    }

    int r8 = lane >> 3, g8 = lane & 7;
    f32x4 acc[4][4];
#pragma unroll
    for (int m = 0; m < 4; ++m)
#pragma unroll
        for (int n = 0; n < 4; ++n) acc[m][n] = (f32x4){0.f, 0.f, 0.f, 0.f};
    for (int jc = 0; jc < 4; ++jc) {
        __syncthreads();
#pragma unroll
        for (int t = 0; t < 8; ++t) {
            int cb = wv * 64 + t * 8;
            int c = cb + r8;
            int gs = g8 ^ (c & 7);
            gld16(Mb + ((size_t)(b * 256 + c)) * LQ_ + jc * 64 + gs * 8, &Ms[cb * 64]);
        }
        __syncthreads();
#pragma unroll
        for (int kk = 0; kk < 2; ++kk) {
            bfrag av[4];
#pragma unroll
            for (int m = 0; m < 4; ++m) {
                int row = m * 16 + (lane & 15);
                int gp = (jc * 8 + kk * 4 + (lane >> 4)) ^ (row & 7);
                av[m] = *(const bfrag*)((const char*)Ps + row * 512 + (gp << 4));
            }
#pragma unroll
            for (int n = 0; n < 4; ++n) {
                int c = wv * 64 + n * 16 + (lane & 15);
                int gb = (kk * 4 + (lane >> 4)) ^ (c & 7);
                bfrag bv = *(const bfrag*)((const char*)Ms + c * 128 + (gb << 4));
#pragma unroll
                for (int m = 0; m < 4; ++m)
                    acc[m][n] = __builtin_amdgcn_mfma_f32_16x16x32_bf16(av[m], bv, acc[m][n], 0, 0, 0);
            }
        }
    }

    __syncthreads();
    float* Cts = (float*)Ms;
    int r4 = lane >> 4, g16 = lane & 15;
#pragma unroll
    for (int t = 0; t < 8; ++t) {
        int db = wv * 32 + t * 4;
        int d = db + r4;
        int gs = g16 ^ (d & 7);
        gld16(C + ((size_t)(b * D_ + d)) * LC_ + i0 + gs * 4, (char*)Cts + db * 256);
    }
    __syncthreads();
    size_t rowb = (size_t)b * LC_ + i0;
    bool isA = (wv < 2);
    int dbase = (wv & 1) * 64;
#pragma unroll
    for (int m = 0; m < 4; ++m) {
        int irow = m * 16 + r4 * 4;
#pragma unroll
        for (int n = 0; n < 4; ++n) {
            int d = dbase + n * 16 + (lane & 15);
            int gc = (m * 4 + r4) ^ (d & 7);
            f4 ct = *(const f4*)((const char*)Cts + d * 256 + (gc << 4));
            f32x4 av = acc[m][n];
            if (isA) {
#pragma unroll
                for (int r = 0; r < 4; ++r) {
                    size_t fb = (rowb + irow + r) * 512;
                    Fb[fb + 128 + d] = f2b(av[r]);
                    Fb[fb + 256 + d] = f2b(ct[r] * av[r]);
                }
            } else {
#pragma unroll
                for (int r = 0; r < 4; ++r) {
                    size_t fb = (rowb + irow + r) * 512;
                    Fb[fb + d]       = f2b(ct[r]);
                    Fb[fb + 384 + d] = f2b(ct[r] * av[r]);
                }
            }
        }
    }
}

// out(d,i) = relu(W(d,k) * F(k,i) + b_res[d]); BM=128 BN=64 BK=64, 4 waves 64x32
__global__ __launch_bounds__(256) void k_projmm(const unsigned short* __restrict__ Wb,
        const unsigned short* __restrict__ Fb, const float* __restrict__ bres,
        float* __restrict__ outp) {
    __shared__ __align__(16) unsigned short Ws[128 * 64];
    __shared__ __align__(16) unsigned short Fs[64 * 64];
    int b = blockIdx.x >> 5, i0 = (blockIdx.x & 31) * 64;
    int tid = threadIdx.x, wv = tid >> 6, lane = tid & 63;
    int wr = wv >> 1, wc = wv & 1;
    int lr = lane >> 3;
    int lk = (lane & 7) * 8;
    f32x4 acc[4][2];
#pragma unroll
    for (int m = 0; m < 4; ++m)
#pragma unroll
        for (int n = 0; n < 2; ++n)
            acc[m][n] = (f32x4){0.f, 0.f, 0.f, 0.f};
    for (int ks = 0; ks < 8; ++ks) {
        int k0 = ks * 64;
        __syncthreads();
#pragma unroll
        for (int cc = 0; cc < 4; ++cc) {
            int c = wv * 4 + cc;
            gld16(Wb + ((size_t)(c * 8 + lr) * 512 + k0 + lk), &Ws[c * 512]);
        }
#pragma unroll
        for (int cc = 0; cc < 2; ++cc) {
            int c = wv * 2 + cc;
            gld16(Fb + ((size_t)(b * LC_ + i0 + c * 8 + lr) * 512 + k0 + lk), &Fs[c * 512]);
        }
        __syncthreads();
#pragma unroll
        for (int kk = 0; kk < 2; ++kk) {
            int ko = kk * 32 + (lane >> 4) * 8;
            bfrag av[4];
#pragma unroll
            for (int m = 0; m < 4; ++m)
                av[m] = *(const bfrag*)&Ws[(wr * 64 + m * 16 + (lane & 15)) * 64 + ko];
#pragma unroll
            for (int n = 0; n < 2; ++n) {
                bfrag bv = *(const bfrag*)&Fs[(wc * 32 + n * 16 + (lane & 15)) * 64 + ko];
#pragma unroll
                for (int m = 0; m < 4; ++m)
                    acc[m][n] = __builtin_amdgcn_mfma_f32_16x16x32_bf16(av[m], bv, acc[m][n], 0, 0, 0);
            }
        }
    }
    int rbase = (lane >> 4) * 4;
#pragma unroll
    for (int m = 0; m < 4; ++m) {
        int dbase = wr * 64 + m * 16 + rbase;
        f4 bias = *(const f4*)&bres[dbase];
#pragma unroll
        for (int n = 0; n < 2; ++n) {
            int i = i0 + wc * 32 + n * 16 + (lane & 15);
#pragma unroll
            for (int r = 0; r < 4; ++r) {
                float v = acc[m][n][r] + bias[r];
                outp[((size_t)(b * D_ + dbase + r)) * LC_ + i] = fmaxf(v, 0.f);
            }
        }
    }
}

extern "C" void kernel_launch(void* const* d_in, const int* in_sizes, int n_in,
                              void* d_out, int out_size, void* d_ws, size_t ws_size,
                              hipStream_t stream) {
    const float* C = (const float*)d_in[0];
    const float* Q = (const float*)d_in[1];
    const int* cmask = (const int*)d_in[2];
    const int* qmask = (const int*)d_in[3];
    const float* w = (const float*)d_in[4];
    const float* W_res = (const float*)d_in[5];
    const float* b_res = (const float*)d_in[6];
    float* out = (float*)d_out;
    float* ws = (float*)d_ws;

    float* Sdot  = ws;                                   // 8388608 f
    float* rC    = Sdot + (size_t)B_ * LC_ * LQ_;        // rcm_c (mask folded)
    float* rQ    = rC + B_ * LC_;                        // rcm_q (mask folded)
    float* pm    = rQ + B_ * LQ_;                        // (unused)
    float* pz    = pm + B_ * 16 * LQ_;                   // (unused)
    float* mcol  = pz + B_ * 16 * LQ_;                   // (unused)
    float* zcol  = mcol + B_ * LQ_;
    float* ScTCt = zcol + B_ * LQ_;                      // (unused)
    float* part  = ScTCt + (size_t)B_ * D_ * LQ_;        // 2097152 f
    float* Abuf  = part + (size_t)4 * B_ * D_ * LQ_;     // Mb + Cbf
    float* Bmbuf = Abuf + (size_t)B_ * LC_ * D_;         // SdotT
    unsigned short* Wb    = (unsigned short*)part;       // after k_red
    unsigned short* Fb    = (unsigned short*)Sdot;       // rowfused in-place
    unsigned short* Mb    = (unsigned short*)Abuf;       // 16*256*256 us
    unsigned short* Cbf   = Mb + (size_t)B_ * 256 * LQ_; // 16*128*2048 us
    unsigned short* SdotT = (unsigned short*)Bmbuf;      // 16*256*2048 us

    k_rvec<<<B_ * LC_ / 256, 256, 0, stream>>>(C, w, cmask, rC, LC_);
    k_rvec<<<B_ * LQ_ / 256, 256, 0, stream>>>(Q, w + D_, qmask, rQ, LQ_);
    k_sdot<<<B_ * 32 * 4, 256, 0, stream>>>(C, Q, w + 2 * D_, Sdot, SdotT, Cbf);
    k_zcol<<<B_ * 64, 256, 0, stream>>>(SdotT, rC, zcol);
    k_sctcmm<<<B_ * 16, 256, 0, stream>>>(SdotT, rC, Cbf, part);
    k_red<<<B_ * 8, 256, 0, stream>>>(part, zcol, Mb);
    k_mb<<<B_ * D_ * LQ_ / 256, 256, 0, stream>>>(Q, Mb);
    k_wbf<<<4 * D_ * D_ / 256, 256, 0, stream>>>(W_res, Wb);
    k_rowfused<<<B_ * 32, 256, 0, stream>>>(Sdot, rQ, Mb, C, Fb);
    k_projmm<<<B_ * 32, 256, 0, stream>>>(Wb, Fb, b_res, out);
}

// Round 6
// 100.362 us; speedup vs baseline: 7.0870x; 1.5807x over previous
//
#include <hip/hip_runtime.h>

// QANet block. B=16 D=128 LC=2048 LQ=256.
// R1: proj -> bf16 MFMA.                         711 -> 318 us
// R2: rowpass -> fused bf16 MFMA.                318 -> 159 us
// R3/R4: column path -> MFMA + bf16 (no max).    318 -> 159 us (k_sdot grew to 77us)
// R5: S computation -> MFMA; fp32 Sdot eliminated:
//   k_prepc/k_prepq: bf16 transposed operands (Cwt[i][d], Qt[j][d]) + Cbf + Mb[0:128]
//   k_sdotmm: SdotT[j][i] = Qt . Cwt via MFMA, LDS-bounce for coalesced stores
//   k_rowfused: phase1 reads SdotT tile from LDS (lane-owns-i), no max-pass,
//               unnormalized e in Ps, 1/z folded into epilogue row-scale
// ws (floats): Fb 8.38M | rC 32K | rQ 4K | zcol 4K | Cwt~part 2.1M | Wb 32K |
//              Mb 0.5M | Cbf 2.1M | SdotT 4.19M | Qt 0.26M   (~70.5 MB)

#define B_ 16
#define D_ 128
#define LC_ 2048
#define LQ_ 256
#define NEGV -1e30f

typedef float f4 __attribute__((ext_vector_type(4)));
typedef float f32x4 __attribute__((ext_vector_type(4)));
typedef short bfrag __attribute__((ext_vector_type(8)));
typedef unsigned short us4 __attribute__((ext_vector_type(4)));

__device__ __forceinline__ unsigned short f2b(float x) {
    unsigned u = __float_as_uint(x);
    u += 0x7fff + ((u >> 16) & 1);
    return (unsigned short)(u >> 16);
}

__device__ __forceinline__ float b2f(short s) {
    return __uint_as_float(((unsigned)(unsigned short)s) << 16);
}

__device__ __forceinline__ void gld16(const void* g, void* l) {
    __builtin_amdgcn_global_load_lds(
        (const __attribute__((address_space(1))) unsigned*)g,
        (__attribute__((address_space(3))) unsigned*)l, 16, 0, 0);
}

// r[b,pos] = sum_d w[d] * X[b,d,pos] + (mask ? 0 : NEG)
__global__ void k_rvec(const float* __restrict__ X, const float* __restrict__ w,
                       const int* __restrict__ mask, float* __restrict__ r, int L) {
    int g = blockIdx.x * 256 + threadIdx.x;
    int b = g / L, pos = g - b * L;
    const float* xp = X + (size_t)b * D_ * L + pos;
    float acc = 0.f;
#pragma unroll 8
    for (int d = 0; d < D_; ++d) acc += w[d] * xp[(size_t)d * L];
    r[g] = acc + (mask[g] ? 0.f : NEGV);
}

// Cbf[b][d][i] = bf16(C); Cwt[b][i][d] = bf16(w3[d]*C)  (LDS transpose)
__global__ __launch_bounds__(256) void k_prepc(const float* __restrict__ C,
        const float* __restrict__ w3, unsigned short* __restrict__ Cbf,
        unsigned short* __restrict__ Cwt) {
    __shared__ float T[128][64];
    int b = blockIdx.x >> 5, i0 = (blockIdx.x & 31) * 64;
    int tid = threadIdx.x;
    int ii = tid & 63, db = tid >> 6;
#pragma unroll
    for (int k = 0; k < 32; ++k) {
        int dd = db + 4 * k;
        float raw = C[((size_t)b * D_ + dd) * LC_ + i0 + ii];
        T[dd][ii] = raw;
        Cbf[((size_t)b * D_ + dd) * LC_ + i0 + ii] = f2b(raw);
    }
    __syncthreads();
    int dq = (tid >> 6) * 32;
#pragma unroll
    for (int m = 0; m < 8; ++m) {
        us4 v;
#pragma unroll
        for (int e = 0; e < 4; ++e) {
            int d = dq + m * 4 + e;
            v[e] = f2b(w3[d] * T[d][ii]);
        }
        *(us4*)&Cwt[((size_t)(b * LC_ + i0 + ii)) * D_ + dq + m * 4] = v;
    }
}

// Qt[b][j][d] = bf16(Q); Mb rows 0..127 = bf16(Q) [d][j]
__global__ __launch_bounds__(256) void k_prepq(const float* __restrict__ Q,
        unsigned short* __restrict__ Qt, unsigned short* __restrict__ Mb) {
    __shared__ float T[128][64];
    int b = blockIdx.x >> 2, j0 = (blockIdx.x & 3) * 64;
    int tid = threadIdx.x;
    int jj = tid & 63, db = tid >> 6;
#pragma unroll
    for (int k = 0; k < 32; ++k) {
        int dd = db + 4 * k;
        float raw = Q[((size_t)b * D_ + dd) * LQ_ + j0 + jj];
        T[dd][jj] = raw;
        Mb[((size_t)(b * 256 + dd)) * LQ_ + j0 + jj] = f2b(raw);
    }
    __syncthreads();
    int dq = (tid >> 6) * 32;
#pragma unroll
    for (int m = 0; m < 8; ++m) {
        us4 v;
#pragma unroll
        for (int e = 0; e < 4; ++e) v[e] = f2b(T[dq + m * 4 + e][jj]);
        *(us4*)&Qt[((size_t)(b * LQ_ + j0 + jj)) * D_ + dq + m * 4] = v;
    }
}

// SdotT[b][j][i] = bf16( sum_d Qt[j][d] * Cwt[i][d] )  via MFMA + LDS bounce
__global__ __launch_bounds__(256) void k_sdotmm(const unsigned short* __restrict__ Qt,
        const unsigned short* __restrict__ Cwt, unsigned short* __restrict__ SdotT) {
    __shared__ __align__(16) unsigned short QA[256 * 128];  // 64KB
    __shared__ __align__(16) unsigned short CB[64 * 128];   // 16KB
    int b = blockIdx.x >> 5, i0 = (blockIdx.x & 31) * 64;
    int tid = threadIdx.x, wv = tid >> 6, lane = tid & 63;
    int l15 = lane & 15, q = lane >> 4;
#pragma unroll
    for (int k = 0; k < 16; ++k) {
        int G = k * 256 + tid;
        int j = G >> 4, g = G & 15;
        gld16(Qt + ((size_t)(b * LQ_ + j)) * D_ + ((g ^ (j & 7)) << 3), &QA[G * 8]);
    }
#pragma unroll
    for (int k = 0; k < 4; ++k) {
        int G = k * 256 + tid;
        int i = G >> 4, g = G & 15;
        gld16(Cwt + ((size_t)(b * LC_ + i0 + i)) * D_ + ((g ^ (i & 7)) << 3), &CB[G * 8]);
    }
    __syncthreads();
    f32x4 acc[4][4];
#pragma unroll
    for (int m = 0; m < 4; ++m)
#pragma unroll
        for (int n = 0; n < 4; ++n) acc[m][n] = (f32x4){0.f, 0.f, 0.f, 0.f};
#pragma unroll
    for (int ks = 0; ks < 4; ++ks) {
        bfrag av[4], bv[4];
#pragma unroll
        for (int m = 0; m < 4; ++m) {
            int jr = wv * 64 + m * 16 + l15;
            av[m] = *(const bfrag*)&QA[jr * 128 + (((ks * 4 + q) ^ (jr & 7)) << 3)];
        }
#pragma unroll
        for (int n = 0; n < 4; ++n) {
            int ir = n * 16 + l15;
            bv[n] = *(const bfrag*)&CB[ir * 128 + (((ks * 4 + q) ^ (ir & 7)) << 3)];
        }
#pragma unroll
        for (int m = 0; m < 4; ++m)
#pragma unroll
            for (int n = 0; n < 4; ++n)
                acc[m][n] = __builtin_amdgcn_mfma_f32_16x16x32_bf16(av[m], bv[n], acc[m][n], 0, 0, 0);
    }
    __syncthreads();
    // bounce D^T tile (rows j, cols i) into this wave's QA quarter: [64 jl][80 us]
    unsigned short* R = &QA[wv * 64 * 128];
#pragma unroll
    for (int m = 0; m < 4; ++m)
#pragma unroll
        for (int n = 0; n < 4; ++n)
#pragma unroll
            for (int r = 0; r < 4; ++r) {
                int jl = m * 16 + q * 4 + r;
                int i = n * 16 + l15;
                *(unsigned short*)((char*)R + jl * 160 + (((i >> 3) ^ (jl & 7)) << 4)
                    + (i & 7) * 2) = f2b(acc[m][n][r]);
            }
    __syncthreads();
#pragma unroll
    for (int k = 0; k < 8; ++k) {
        int G = k * 64 + lane;
        int jl = G >> 3, gi = G & 7;
        bfrag v = *(const bfrag*)((const char*)R + jl * 160 + ((gi ^ (jl & 7)) << 4));
        *(bfrag*)&SdotT[((size_t)(b * LQ_ + wv * 64 + jl)) * LC_ + i0 + gi * 8] = v;
    }
}

// zcol[b,j] = sum_i exp(SdotT[b,j,i] + rcm[b,i])
__global__ __launch_bounds__(256) void k_zcol(const unsigned short* __restrict__ SdotT,
        const float* __restrict__ rcm, float* __restrict__ zcol) {
    int b = blockIdx.x >> 6, j4 = blockIdx.x & 63;
    int wv = threadIdx.x >> 6, lane = threadIdx.x & 63;
    int j = j4 * 4 + wv;
    const unsigned short* row = SdotT + ((size_t)(b * LQ_ + j)) * LC_;
    const float* rc = rcm + b * LC_;
    float z = 0.f;
#pragma unroll
    for (int it = 0; it < 4; ++it) {
        int i = it * 512 + lane * 8;
        bfrag sd = *(const bfrag*)&row[i];
        f4 r0 = *(const f4*)&rc[i];
        f4 r1 = *(const f4*)&rc[i + 4];
#pragma unroll
        for (int e = 0; e < 8; ++e) {
            float f = b2f(sd[e]) + (e < 4 ? r0[e] : r1[e - 4]);
            z += __expf(f);
        }
    }
#pragma unroll
    for (int s = 32; s > 0; s >>= 1) z += __shfl_xor(z, s, 64);
    if (lane == 0) zcol[b * LQ_ + j] = z;
}

// part[ks][b][j][d] = sum_{i in ks*512..} exp(SdotT+rcm) * Cbf[d][i]
__global__ __launch_bounds__(256) void k_sctcmm(
        const unsigned short* __restrict__ SdotT, const float* __restrict__ rcm,
        const unsigned short* __restrict__ Cbf, float* __restrict__ part) {
    __shared__ __align__(16) unsigned short Cs[128 * 64];
    int bid = blockIdx.x;
    int ks = bid & 3, jt = (bid >> 2) & 3, b = bid >> 4;
    int j0 = jt * 64;
    int tid = threadIdx.x, wv = tid >> 6, lane = tid & 63;
    int jw = wv & 1, dw = wv >> 1;
    int l15 = lane & 15, l4 = lane >> 4;
    size_t sdbase0 = ((size_t)(b * LQ_ + j0 + jw * 32 + l15)) * LC_;
    size_t sdbase1 = sdbase0 + (size_t)16 * LC_;
    f32x4 acc[2][4];
#pragma unroll
    for (int mm = 0; mm < 2; ++mm)
#pragma unroll
        for (int nn = 0; nn < 4; ++nn) acc[mm][nn] = (f32x4){0.f, 0.f, 0.f, 0.f};
    for (int c = 0; c < 8; ++c) {
        int ic = ks * 512 + c * 64;
        bfrag stg[4];
        int rr[4], gg[4];
#pragma unroll
        for (int t = 0; t < 4; ++t) {
            int gi = t * 256 + tid;
            rr[t] = gi >> 3;
            gg[t] = gi & 7;
            stg[t] = *(const bfrag*)&Cbf[((size_t)(b * D_ + rr[t])) * LC_ + ic + gg[t] * 8];
        }
        bfrag afr[2][2];
#pragma unroll
        for (int kk = 0; kk < 2; ++kk) {
            int ib = ic + kk * 32 + l4 * 8;
            f4 r0 = *(const f4*)&rcm[b * LC_ + ib];
            f4 r1 = *(const f4*)&rcm[b * LC_ + ib + 4];
#pragma unroll
            for (int mm = 0; mm < 2; ++mm) {
                bfrag sd = *(const bfrag*)&SdotT[(mm ? sdbase1 : sdbase0) + ib];
                bfrag fr;
#pragma unroll
                for (int e = 0; e < 8; ++e)
                    fr[e] = (short)f2b(__expf(b2f(sd[e]) + (e < 4 ? r0[e] : r1[e - 4])));
                afr[mm][kk] = fr;
            }
        }
        __syncthreads();
#pragma unroll
        for (int t = 0; t < 4; ++t)
            *(bfrag*)&Cs[rr[t] * 64 + ((gg[t] ^ (rr[t] & 7)) << 3)] = stg[t];
        __syncthreads();
#pragma unroll
        for (int kk = 0; kk < 2; ++kk)
#pragma unroll
            for (int nn = 0; nn < 4; ++nn) {
                int d = dw * 64 + nn * 16 + l15;
                int g = kk * 4 + l4;
                bfrag bv = *(const bfrag*)&Cs[d * 64 + ((g ^ (d & 7)) << 3)];
#pragma unroll
                for (int mm = 0; mm < 2; ++mm)
                    acc[mm][nn] = __builtin_amdgcn_mfma_f32_16x16x32_bf16(afr[mm][kk], bv, acc[mm][nn], 0, 0, 0);
            }
    }
#pragma unroll
    for (int mm = 0; mm < 2; ++mm)
#pragma unroll
        for (int nn = 0; nn < 4; ++nn) {
            int d = dw * 64 + nn * 16 + l15;
#pragma unroll
            for (int r = 0; r < 4; ++r) {
                int j = j0 + jw * 32 + mm * 16 + l4 * 4 + r;
                part[((size_t)(ks * B_ + b) * LQ_ + j) * D_ + d] = acc[mm][nn][r];
            }
        }
}

// Mb[b][128+d][j] = bf16( sum_ks part / zcol )  via LDS transpose
__global__ __launch_bounds__(256) void k_red(const float* __restrict__ part,
        const float* __restrict__ zcol, unsigned short* __restrict__ Mb) {
    __shared__ float Ts[64][68];
    int bid = blockIdx.x;
    int dt = bid & 1, jt = (bid >> 1) & 3, b = bid >> 3;
    int j0 = jt * 64, d0 = dt * 64;
    int tid = threadIdx.x;
    {
        int jj = tid >> 2, dq = (tid & 3) * 16;
        float rz = 1.0f / zcol[b * LQ_ + j0 + jj];
        f4 s[4];
#pragma unroll
        for (int q = 0; q < 4; ++q) s[q] = (f4){0.f, 0.f, 0.f, 0.f};
#pragma unroll
        for (int ks = 0; ks < 4; ++ks) {
            size_t base = ((size_t)(ks * B_ + b) * LQ_ + j0 + jj) * D_ + d0 + dq;
#pragma unroll
            for (int q = 0; q < 4; ++q) s[q] += *(const f4*)&part[base + q * 4];
        }
#pragma unroll
        for (int q = 0; q < 4; ++q) {
            f4 v = {s[q][0] * rz, s[q][1] * rz, s[q][2] * rz, s[q][3] * rz};
            *(f4*)&Ts[jj][dq + q * 4] = v;
        }
    }
    __syncthreads();
    {
        int dd = tid >> 2, jq = (tid & 3) * 16;
        us4 o0, o1, o2, o3;
#pragma unroll
        for (int q = 0; q < 4; ++q) o0[q] = f2b(Ts[jq + q][dd]);
#pragma unroll
        for (int q = 0; q < 4; ++q) o1[q] = f2b(Ts[jq + 4 + q][dd]);
#pragma unroll
        for (int q = 0; q < 4; ++q) o2[q] = f2b(Ts[jq + 8 + q][dd]);
#pragma unroll
        for (int q = 0; q < 4; ++q) o3[q] = f2b(Ts[jq + 12 + q][dd]);
        unsigned short* dst = Mb + ((size_t)(b * 256 + 128 + d0 + dd)) * LQ_ + j0 + jq;
        *(us4*)&dst[0] = o0; *(us4*)&dst[4] = o1; *(us4*)&dst[8] = o2; *(us4*)&dst[12] = o3;
    }
}

// Wb = bf16(W_res), layout [d][f]
__global__ void k_wbf(const float* __restrict__ W, unsigned short* __restrict__ Wb) {
    int o = blockIdx.x * 256 + threadIdx.x;
    Wb[o] = f2b(W[o]);
}

// Fused: row softmax (from SdotT, no max-pass) -> [A|Bm]=P@M -> Fb
__global__ __launch_bounds__(256) void k_rowfused(
        const unsigned short* __restrict__ SdotT, const float* __restrict__ rQm,
        const unsigned short* __restrict__ Mb,
        const float* __restrict__ C, unsigned short* __restrict__ Fb) {
    __shared__ __align__(16) unsigned short Ps[64 * 256];  // unnormalized e, swizzled
    __shared__ __align__(16) unsigned short Ms[256 * 64];  // Sts -> M chunks -> Cts
    __shared__ float Zp[4][64];
    __shared__ float rzs[64];
    int b = blockIdx.x >> 5, i0 = (blockIdx.x & 31) * 64;
    int tid = threadIdx.x, wv = tid >> 6, lane = tid & 63;

    // phase 0: stage SdotT tile [256 j][64 i] (linear; reads are conflict-free)
#pragma unroll
    for (int k = 0; k < 8; ++k) {
        int G = k * 256 + tid;
        int j = G >> 3, g = G & 7;
        gld16(SdotT + ((size_t)(b * LQ_ + j)) * LC_ + i0 + g * 8, &Ms[G * 8]);
    }
    __syncthreads();
    // phase 1: lane owns i=lane; wave wv covers j in [wv*64, wv*64+64)
    float z = 0.f;
    for (int jj = 0; jj < 64; ++jj) {
        int j = wv * 64 + jj;
        float s = b2f((short)Ms[j * 64 + lane]);
        float e = __expf(s + rQm[b * LQ_ + j]);
        z += e;
        *(unsigned short*)((char*)Ps + lane * 512 + (((j >> 3) ^ (lane & 7)) << 4)
            + (j & 7) * 2) = f2b(e);
    }
    Zp[wv][lane] = z;
    __syncthreads();
    if (tid < 64) rzs[tid] = 1.f / (Zp[0][tid] + Zp[1][tid] + Zp[2][tid] + Zp[3][tid]);

    int r8 = lane >> 3, g8 = lane & 7;
    f32x4 acc[4][4];
#pragma unroll
    for (int m = 0; m < 4; ++m)
#pragma unroll
        for (int n = 0; n < 4; ++n) acc[m][n] = (f32x4){0.f, 0.f, 0.f, 0.f};
    for (int jc = 0; jc < 4; ++jc) {
        __syncthreads();
#pragma unroll
        for (int t = 0; t < 8; ++t) {
            int cb = wv * 64 + t * 8;
            int c = cb + r8;
            int gs = g8 ^ (c & 7);
            gld16(Mb + ((size_t)(b * 256 + c)) * LQ_ + jc * 64 + gs * 8, &Ms[cb * 64]);
        }
        __syncthreads();
#pragma unroll
        for (int kk = 0; kk < 2; ++kk) {
            bfrag av[4];
#pragma unroll
            for (int m = 0; m < 4; ++m) {
                int row = m * 16 + (lane & 15);
                int gp = (jc * 8 + kk * 4 + (lane >> 4)) ^ (row & 7);
                av[m] = *(const bfrag*)((const char*)Ps + row * 512 + (gp << 4));
            }
#pragma unroll
            for (int n = 0; n < 4; ++n) {
                int c = wv * 64 + n * 16 + (lane & 15);
                int gb = (kk * 4 + (lane >> 4)) ^ (c & 7);
                bfrag bv = *(const bfrag*)((const char*)Ms + c * 128 + (gb << 4));
#pragma unroll
                for (int m = 0; m < 4; ++m)
                    acc[m][n] = __builtin_amdgcn_mfma_f32_16x16x32_bf16(av[m], bv, acc[m][n], 0, 0, 0);
            }
        }
    }

    __syncthreads();
    float* Cts = (float*)Ms;
    int r4 = lane >> 4, g16 = lane & 15;
#pragma unroll
    for (int t = 0; t < 8; ++t) {
        int db = wv * 32 + t * 4;
        int d = db + r4;
        int gs = g16 ^ (d & 7);
        gld16(C + ((size_t)(b * D_ + d)) * LC_ + i0 + gs * 4, (char*)Cts + db * 256);
    }
    __syncthreads();
    size_t rowb = (size_t)b * LC_ + i0;
    bool isA = (wv < 2);
    int dbase = (wv & 1) * 64;
#pragma unroll
    for (int m = 0; m < 4; ++m) {
        int irow = m * 16 + r4 * 4;
        f4 rzv = *(const f4*)&rzs[irow];
#pragma unroll
        for (int n = 0; n < 4; ++n) {
            int d = dbase + n * 16 + (lane & 15);
            int gc = (m * 4 + r4) ^ (d & 7);
            f4 ct = *(const f4*)((const char*)Cts + d * 256 + (gc << 4));
            f32x4 av = acc[m][n];
            float as[4];
#pragma unroll
            for (int r = 0; r < 4; ++r) as[r] = av[r] * rzv[r];
            if (isA) {
#pragma unroll
                for (int r = 0; r < 4; ++r) {
                    size_t fb = (rowb + irow + r) * 512;
                    Fb[fb + 128 + d] = f2b(as[r]);
                    Fb[fb + 256 + d] = f2b(ct[r] * as[r]);
                }
            } else {
#pragma unroll
                for (int r = 0; r < 4; ++r) {
                    size_t fb = (rowb + irow + r) * 512;
                    Fb[fb + d]       = f2b(ct[r]);
                    Fb[fb + 384 + d] = f2b(ct[r] * as[r]);
                }
            }
        }
    }
}

// out(d,i) = relu(W(d,k) * F(k,i) + b_res[d])
__global__ __launch_bounds__(256) void k_projmm(const unsigned short* __restrict__ Wb,
        const unsigned short* __restrict__ Fb, const float* __restrict__ bres,
        float* __restrict__ outp) {
    __shared__ __align__(16) unsigned short Ws[128 * 64];
    __shared__ __align__(16) unsigned short Fs[64 * 64];
    int b = blockIdx.x >> 5, i0 = (blockIdx.x & 31) * 64;
    int tid = threadIdx.x, wv = tid >> 6, lane = tid & 63;
    int wr = wv >> 1, wc = wv & 1;
    int lr = lane >> 3;
    int lk = (lane & 7) * 8;
    f32x4 acc[4][2];
#pragma unroll
    for (int m = 0; m < 4; ++m)
#pragma unroll
        for (int n = 0; n < 2; ++n)
            acc[m][n] = (f32x4){0.f, 0.f, 0.f, 0.f};
    for (int ks = 0; ks < 8; ++ks) {
        int k0 = ks * 64;
        __syncthreads();
#pragma unroll
        for (int cc = 0; cc < 4; ++cc) {
            int c = wv * 4 + cc;
            gld16(Wb + ((size_t)(c * 8 + lr) * 512 + k0 + lk), &Ws[c * 512]);
        }
#pragma unroll
        for (int cc = 0; cc < 2; ++cc) {
            int c = wv * 2 + cc;
            gld16(Fb + ((size_t)(b * LC_ + i0 + c * 8 + lr) * 512 + k0 + lk), &Fs[c * 512]);
        }
        __syncthreads();
#pragma unroll
        for (int kk = 0; kk < 2; ++kk) {
            int ko = kk * 32 + (lane >> 4) * 8;
            bfrag av[4];
#pragma unroll
            for (int m = 0; m < 4; ++m)
                av[m] = *(const bfrag*)&Ws[(wr * 64 + m * 16 + (lane & 15)) * 64 + ko];
#pragma unroll
            for (int n = 0; n < 2; ++n) {
                bfrag bv = *(const bfrag*)&Fs[(wc * 32 + n * 16 + (lane & 15)) * 64 + ko];
#pragma unroll
                for (int m = 0; m < 4; ++m)
                    acc[m][n] = __builtin_amdgcn_mfma_f32_16x16x32_bf16(av[m], bv, acc[m][n], 0, 0, 0);
            }
        }
    }
    int rbase = (lane >> 4) * 4;
#pragma unroll
    for (int m = 0; m < 4; ++m) {
        int dbase = wr * 64 + m * 16 + rbase;
        f4 bias = *(const f4*)&bres[dbase];
#pragma unroll
        for (int n = 0; n < 2; ++n) {
            int i = i0 + wc * 32 + n * 16 + (lane & 15);
#pragma unroll
            for (int r = 0; r < 4; ++r) {
                float v = acc[m][n][r] + bias[r];
                outp[((size_t)(b * D_ + dbase + r)) * LC_ + i] = fmaxf(v, 0.f);
            }
        }
    }
}

extern "C" void kernel_launch(void* const* d_in, const int* in_sizes, int n_in,
                              void* d_out, int out_size, void* d_ws, size_t ws_size,
                              hipStream_t stream) {
    const float* C = (const float*)d_in[0];
    const float* Q = (const float*)d_in[1];
    const int* cmask = (const int*)d_in[2];
    const int* qmask = (const int*)d_in[3];
    const float* w = (const float*)d_in[4];
    const float* W_res = (const float*)d_in[5];
    const float* b_res = (const float*)d_in[6];
    float* out = (float*)d_out;
    float* ws = (float*)d_ws;

    float* fb_f  = ws;                                   // Fb bf16 (8,388,608 f)
    float* rC    = fb_f + (size_t)8388608;               // 32768 f
    float* rQ    = rC + 32768;                           // 4096 f
    float* zcol  = rQ + 4096;                            // 4096 f
    float* cwtp  = zcol + 4096;                          // Cwt bf16 then part fp32 (2,097,152 f)
    float* wbf_f = cwtp + (size_t)2097152;               // Wb (32768 f)
    float* mb_f  = wbf_f + 32768;                        // Mb (524288 f)
    float* cbf_f = mb_f + 524288;                        // Cbf (2,097,152 f)
    float* sdt_f = cbf_f + (size_t)2097152;              // SdotT (4,194,304 f)
    float* qt_f  = sdt_f + (size_t)4194304;              // Qt (262,144 f)

    unsigned short* Fb    = (unsigned short*)fb_f;
    unsigned short* Cwt   = (unsigned short*)cwtp;
    float*          part  = cwtp;                        // alias: Cwt dead after k_sdotmm
    unsigned short* Wb    = (unsigned short*)wbf_f;
    unsigned short* Mb    = (unsigned short*)mb_f;
    unsigned short* Cbf   = (unsigned short*)cbf_f;
    unsigned short* SdotT = (unsigned short*)sdt_f;
    unsigned short* Qt    = (unsigned short*)qt_f;

    k_rvec<<<B_ * LC_ / 256, 256, 0, stream>>>(C, w, cmask, rC, LC_);
    k_rvec<<<B_ * LQ_ / 256, 256, 0, stream>>>(Q, w + D_, qmask, rQ, LQ_);
    k_prepc<<<B_ * 32, 256, 0, stream>>>(C, w + 2 * D_, Cbf, Cwt);
    k_prepq<<<B_ * 4, 256, 0, stream>>>(Q, Qt, Mb);
    k_sdotmm<<<B_ * 32, 256, 0, stream>>>(Qt, Cwt, SdotT);
    k_zcol<<<B_ * 64, 256, 0, stream>>>(SdotT, rC, zcol);
    k_sctcmm<<<B_ * 16, 256, 0, stream>>>(SdotT, rC, Cbf, part);
    k_red<<<B_ * 8, 256, 0, stream>>>(part, zcol, Mb);
    k_wbf<<<4 * D_ * D_ / 256, 256, 0, stream>>>(W_res, Wb);
    k_rowfused<<<B_ * 32, 256, 0, stream>>>(SdotT, rQ, Mb, C, Fb);
    k_projmm<<<B_ * 32, 256, 0, stream>>>(Wb, Fb, b_res, out);
}

// Round 7
// 84.509 us; speedup vs baseline: 8.4164x; 1.1876x over previous
//
#include <hip/hip_runtime.h>

// QANet block. B=16 D=128 LC=2048 LQ=256.
// R1: proj -> bf16 MFMA.                         711 -> 318 us
// R2: rowpass -> fused bf16 MFMA.                318 -> 159 us
// R3/R4: column path -> MFMA + bf16 (no max).    159 us
// R5: S -> MFMA (k_sdotmm), fp32 Sdot gone.      159 -> 100 us
// R6: fusion round, 11 -> 6 dispatches:
//   k_prepc  += rC reduction + Wb cast        (kills k_rvec(C), k_wbf)
//   k_prepq  += rQ reduction                  (kills k_rvec(Q))
//   k_sctcmm += paz z-partials                (kills k_zcol)
//   k_rowproj = rowfused + projmm in one block: F tile lives in LDS
//               (kills Fb 67MB round-trip + fp32 C reload; swizzled W/F reads)
// ws (floats): rC 32K | rQ 4K | paz 16K | Cwt~part 2.1M | Wb 32K | Mb 0.5M |
//              Cbf 2.1M | SdotT 4.19M | Qt 0.26M   (~37 MB)

#define B_ 16
#define D_ 128
#define LC_ 2048
#define LQ_ 256
#define NEGV -1e30f

typedef float f4 __attribute__((ext_vector_type(4)));
typedef float f32x4 __attribute__((ext_vector_type(4)));
typedef short bfrag __attribute__((ext_vector_type(8)));
typedef unsigned short us4 __attribute__((ext_vector_type(4)));

__device__ __forceinline__ unsigned short f2b(float x) {
    unsigned u = __float_as_uint(x);
    u += 0x7fff + ((u >> 16) & 1);
    return (unsigned short)(u >> 16);
}

__device__ __forceinline__ float b2f(short s) {
    return __uint_as_float(((unsigned)(unsigned short)s) << 16);
}

__device__ __forceinline__ void gld16(const void* g, void* l) {
    __builtin_amdgcn_global_load_lds(
        (const __attribute__((address_space(1))) unsigned*)g,
        (__attribute__((address_space(3))) unsigned*)l, 16, 0, 0);
}

// Cbf[b][d][i]=bf16(C); Cwt[b][i][d]=bf16(w3*C); rC[b][i]=sum_d w1*C + mask; Wb cast
__global__ __launch_bounds__(256) void k_prepc(const float* __restrict__ C,
        const float* __restrict__ w, const int* __restrict__ cmask,
        const float* __restrict__ W_res,
        unsigned short* __restrict__ Cbf, unsigned short* __restrict__ Cwt,
        unsigned short* __restrict__ Wb, float* __restrict__ rC) {
    __shared__ float T[128][64];
    __shared__ float red[4][64];
    int b = blockIdx.x >> 5, i0 = (blockIdx.x & 31) * 64;
    int tid = threadIdx.x;
    int ii = tid & 63, db = tid >> 6;
    if (tid < 128) {
        int wo = blockIdx.x * 128 + tid;
        Wb[wo] = f2b(W_res[wo]);
    }
#pragma unroll
    for (int k = 0; k < 32; ++k) {
        int dd = db + 4 * k;
        float raw = C[((size_t)b * D_ + dd) * LC_ + i0 + ii];
        T[dd][ii] = raw;
        Cbf[((size_t)b * D_ + dd) * LC_ + i0 + ii] = f2b(raw);
    }
    __syncthreads();
    {
        float p = 0.f;
#pragma unroll
        for (int k = 0; k < 32; ++k) p += w[db * 32 + k] * T[db * 32 + k][ii];
        red[db][ii] = p;
    }
    int dq = db * 32;
#pragma unroll
    for (int m = 0; m < 8; ++m) {
        us4 v;
#pragma unroll
        for (int e = 0; e < 4; ++e) {
            int d = dq + m * 4 + e;
            v[e] = f2b(w[2 * D_ + d] * T[d][ii]);
        }
        *(us4*)&Cwt[((size_t)(b * LC_ + i0 + ii)) * D_ + dq + m * 4] = v;
    }
    __syncthreads();
    if (tid < 64) {
        int gi = b * LC_ + i0 + tid;
        rC[gi] = red[0][tid] + red[1][tid] + red[2][tid] + red[3][tid]
               + (cmask[gi] ? 0.f : NEGV);
    }
}

// Qt[b][j][d]=bf16(Q); Mb rows 0..127 = bf16(Q)[d][j]; rQ[b][j]=sum_d w2*Q + mask
__global__ __launch_bounds__(256) void k_prepq(const float* __restrict__ Q,
        const float* __restrict__ w, const int* __restrict__ qmask,
        unsigned short* __restrict__ Qt, unsigned short* __restrict__ Mb,
        float* __restrict__ rQ) {
    __shared__ float T[128][64];
    __shared__ float red[4][64];
    int b = blockIdx.x >> 2, j0 = (blockIdx.x & 3) * 64;
    int tid = threadIdx.x;
    int jj = tid & 63, db = tid >> 6;
#pragma unroll
    for (int k = 0; k < 32; ++k) {
        int dd = db + 4 * k;
        float raw = Q[((size_t)b * D_ + dd) * LQ_ + j0 + jj];
        T[dd][jj] = raw;
        Mb[((size_t)(b * 256 + dd)) * LQ_ + j0 + jj] = f2b(raw);
    }
    __syncthreads();
    {
        float p = 0.f;
#pragma unroll
        for (int k = 0; k < 32; ++k) p += w[D_ + db * 32 + k] * T[db * 32 + k][jj];
        red[db][jj] = p;
    }
    int dq = db * 32;
#pragma unroll
    for (int m = 0; m < 8; ++m) {
        us4 v;
#pragma unroll
        for (int e = 0; e < 4; ++e) v[e] = f2b(T[dq + m * 4 + e][jj]);
        *(us4*)&Qt[((size_t)(b * LQ_ + j0 + jj)) * D_ + dq + m * 4] = v;
    }
    __syncthreads();
    if (tid < 64) {
        int gj = b * LQ_ + j0 + tid;
        rQ[gj] = red[0][tid] + red[1][tid] + red[2][tid] + red[3][tid]
               + (qmask[gj] ? 0.f : NEGV);
    }
}

// SdotT[b][j][i] = bf16( sum_d Qt[j][d] * Cwt[i][d] )  via MFMA + LDS bounce
__global__ __launch_bounds__(256) void k_sdotmm(const unsigned short* __restrict__ Qt,
        const unsigned short* __restrict__ Cwt, unsigned short* __restrict__ SdotT) {
    __shared__ __align__(16) unsigned short QA[256 * 128];
    __shared__ __align__(16) unsigned short CB[64 * 128];
    int b = blockIdx.x >> 5, i0 = (blockIdx.x & 31) * 64;
    int tid = threadIdx.x, wv = tid >> 6, lane = tid & 63;
    int l15 = lane & 15, q = lane >> 4;
#pragma unroll
    for (int k = 0; k < 16; ++k) {
        int G = k * 256 + tid;
        int j = G >> 4, g = G & 15;
        gld16(Qt + ((size_t)(b * LQ_ + j)) * D_ + ((g ^ (j & 7)) << 3), &QA[G * 8]);
    }
#pragma unroll
    for (int k = 0; k < 4; ++k) {
        int G = k * 256 + tid;
        int i = G >> 4, g = G & 15;
        gld16(Cwt + ((size_t)(b * LC_ + i0 + i)) * D_ + ((g ^ (i & 7)) << 3), &CB[G * 8]);
    }
    __syncthreads();
    f32x4 acc[4][4];
#pragma unroll
    for (int m = 0; m < 4; ++m)
#pragma unroll
        for (int n = 0; n < 4; ++n) acc[m][n] = (f32x4){0.f, 0.f, 0.f, 0.f};
#pragma unroll
    for (int ks = 0; ks < 4; ++ks) {
        bfrag av[4], bv[4];
#pragma unroll
        for (int m = 0; m < 4; ++m) {
            int jr = wv * 64 + m * 16 + l15;
            av[m] = *(const bfrag*)&QA[jr * 128 + (((ks * 4 + q) ^ (jr & 7)) << 3)];
        }
#pragma unroll
        for (int n = 0; n < 4; ++n) {
            int ir = n * 16 + l15;
            bv[n] = *(const bfrag*)&CB[ir * 128 + (((ks * 4 + q) ^ (ir & 7)) << 3)];
        }
#pragma unroll
        for (int m = 0; m < 4; ++m)
#pragma unroll
            for (int n = 0; n < 4; ++n)
                acc[m][n] = __builtin_amdgcn_mfma_f32_16x16x32_bf16(av[m], bv[n], acc[m][n], 0, 0, 0);
    }
    __syncthreads();
    unsigned short* R = &QA[wv * 64 * 128];
#pragma unroll
    for (int m = 0; m < 4; ++m)
#pragma unroll
        for (int n = 0; n < 4; ++n)
#pragma unroll
            for (int r = 0; r < 4; ++r) {
                int jl = m * 16 + q * 4 + r;
                int i = n * 16 + l15;
                *(unsigned short*)((char*)R + jl * 160 + (((i >> 3) ^ (jl & 7)) << 4)
                    + (i & 7) * 2) = f2b(acc[m][n][r]);
            }
    __syncthreads();
#pragma unroll
    for (int k = 0; k < 8; ++k) {
        int G = k * 64 + lane;
        int jl = G >> 3, gi = G & 7;
        bfrag v = *(const bfrag*)((const char*)R + jl * 160 + ((gi ^ (jl & 7)) << 4));
        *(bfrag*)&SdotT[((size_t)(b * LQ_ + wv * 64 + jl)) * LC_ + i0 + gi * 8] = v;
    }
}

// part[ks][b][j][d] = sum_i exp(SdotT+rcm)*Cbf[d][i]; paz[ks][b][j] = sum_i exp(..)
__global__ __launch_bounds__(256) void k_sctcmm(
        const unsigned short* __restrict__ SdotT, const float* __restrict__ rcm,
        const unsigned short* __restrict__ Cbf, float* __restrict__ part,
        float* __restrict__ paz) {
    __shared__ __align__(16) unsigned short Cs[128 * 64];
    int bid = blockIdx.x;
    int ks = bid & 3, jt = (bid >> 2) & 3, b = bid >> 4;
    int j0 = jt * 64;
    int tid = threadIdx.x, wv = tid >> 6, lane = tid & 63;
    int jw = wv & 1, dw = wv >> 1;
    int l15 = lane & 15, l4 = lane >> 4;
    size_t sdbase0 = ((size_t)(b * LQ_ + j0 + jw * 32 + l15)) * LC_;
    size_t sdbase1 = sdbase0 + (size_t)16 * LC_;
    f32x4 acc[2][4];
#pragma unroll
    for (int mm = 0; mm < 2; ++mm)
#pragma unroll
        for (int nn = 0; nn < 4; ++nn) acc[mm][nn] = (f32x4){0.f, 0.f, 0.f, 0.f};
    float zac0 = 0.f, zac1 = 0.f;
    for (int c = 0; c < 8; ++c) {
        int ic = ks * 512 + c * 64;
        bfrag stg[4];
        int rr[4], gg[4];
#pragma unroll
        for (int t = 0; t < 4; ++t) {
            int gi = t * 256 + tid;
            rr[t] = gi >> 3;
            gg[t] = gi & 7;
            stg[t] = *(const bfrag*)&Cbf[((size_t)(b * D_ + rr[t])) * LC_ + ic + gg[t] * 8];
        }
        bfrag afr[2][2];
#pragma unroll
        for (int kk = 0; kk < 2; ++kk) {
            int ib = ic + kk * 32 + l4 * 8;
            f4 r0 = *(const f4*)&rcm[b * LC_ + ib];
            f4 r1 = *(const f4*)&rcm[b * LC_ + ib + 4];
#pragma unroll
            for (int mm = 0; mm < 2; ++mm) {
                bfrag sd = *(const bfrag*)&SdotT[(mm ? sdbase1 : sdbase0) + ib];
                bfrag fr;
                float zl = 0.f;
#pragma unroll
                for (int e = 0; e < 8; ++e) {
                    float pe = __expf(b2f(sd[e]) + (e < 4 ? r0[e] : r1[e - 4]));
                    fr[e] = (short)f2b(pe);
                    zl += pe;
                }
                if (mm == 0) zac0 += zl; else zac1 += zl;
                afr[mm][kk] = fr;
            }
        }
        __syncthreads();
#pragma unroll
        for (int t = 0; t < 4; ++t)
            *(bfrag*)&Cs[rr[t] * 64 + ((gg[t] ^ (rr[t] & 7)) << 3)] = stg[t];
        __syncthreads();
#pragma unroll
        for (int kk = 0; kk < 2; ++kk)
#pragma unroll
            for (int nn = 0; nn < 4; ++nn) {
                int d = dw * 64 + nn * 16 + l15;
                int g = kk * 4 + l4;
                bfrag bv = *(const bfrag*)&Cs[d * 64 + ((g ^ (d & 7)) << 3)];
#pragma unroll
                for (int mm = 0; mm < 2; ++mm)
                    acc[mm][nn] = __builtin_amdgcn_mfma_f32_16x16x32_bf16(afr[mm][kk], bv, acc[mm][nn], 0, 0, 0);
            }
    }
    // z partial reduce across the 4 i-slot lanes (l4) and write (dw==0 waves only)
    zac0 += __shfl_xor(zac0, 16, 64); zac0 += __shfl_xor(zac0, 32, 64);
    zac1 += __shfl_xor(zac1, 16, 64); zac1 += __shfl_xor(zac1, 32, 64);
    if (dw == 0 && l4 == 0) {
        size_t zb = ((size_t)(ks * B_ + b)) * LQ_ + j0 + jw * 32 + l15;
        paz[zb] = zac0;
        paz[zb + 16] = zac1;
    }
#pragma unroll
    for (int mm = 0; mm < 2; ++mm)
#pragma unroll
        for (int nn = 0; nn < 4; ++nn) {
            int d = dw * 64 + nn * 16 + l15;
#pragma unroll
            for (int r = 0; r < 4; ++r) {
                int j = j0 + jw * 32 + mm * 16 + l4 * 4 + r;
                part[((size_t)(ks * B_ + b) * LQ_ + j) * D_ + d] = acc[mm][nn][r];
            }
        }
}

// Mb[b][128+d][j] = bf16( sum_ks part / sum_ks paz )  via LDS transpose
__global__ __launch_bounds__(256) void k_red(const float* __restrict__ part,
        const float* __restrict__ paz, unsigned short* __restrict__ Mb) {
    __shared__ float Ts[64][68];
    int bid = blockIdx.x;
    int dt = bid & 1, jt = (bid >> 1) & 3, b = bid >> 3;
    int j0 = jt * 64, d0 = dt * 64;
    int tid = threadIdx.x;
    {
        int jj = tid >> 2, dq = (tid & 3) * 16;
        float zs = paz[((size_t)(0 * B_ + b)) * LQ_ + j0 + jj]
                 + paz[((size_t)(1 * B_ + b)) * LQ_ + j0 + jj]
                 + paz[((size_t)(2 * B_ + b)) * LQ_ + j0 + jj]
                 + paz[((size_t)(3 * B_ + b)) * LQ_ + j0 + jj];
        float rz = 1.0f / zs;
        f4 s[4];
#pragma unroll
        for (int q = 0; q < 4; ++q) s[q] = (f4){0.f, 0.f, 0.f, 0.f};
#pragma unroll
        for (int ks = 0; ks < 4; ++ks) {
            size_t base = ((size_t)(ks * B_ + b) * LQ_ + j0 + jj) * D_ + d0 + dq;
#pragma unroll
            for (int q = 0; q < 4; ++q) s[q] += *(const f4*)&part[base + q * 4];
        }
#pragma unroll
        for (int q = 0; q < 4; ++q) {
            f4 v = {s[q][0] * rz, s[q][1] * rz, s[q][2] * rz, s[q][3] * rz};
            *(f4*)&Ts[jj][dq + q * 4] = v;
        }
    }
    __syncthreads();
    {
        int dd = tid >> 2, jq = (tid & 3) * 16;
        us4 o0, o1, o2, o3;
#pragma unroll
        for (int q = 0; q < 4; ++q) o0[q] = f2b(Ts[jq + q][dd]);
#pragma unroll
        for (int q = 0; q < 4; ++q) o1[q] = f2b(Ts[jq + 4 + q][dd]);
#pragma unroll
        for (int q = 0; q < 4; ++q) o2[q] = f2b(Ts[jq + 8 + q][dd]);
#pragma unroll
        for (int q = 0; q < 4; ++q) o3[q] = f2b(Ts[jq + 12 + q][dd]);
        unsigned short* dst = Mb + ((size_t)(b * 256 + 128 + d0 + dd)) * LQ_ + j0 + jq;
        *(us4*)&dst[0] = o0; *(us4*)&dst[4] = o1; *(us4*)&dst[8] = o2; *(us4*)&dst[12] = o3;
    }
}

// Fused: row softmax -> acc=[A|Bm]=P@M -> F tile in LDS -> out = relu(W·F + b)
__global__ __launch_bounds__(256) void k_rowproj(
        const unsigned short* __restrict__ SdotT, const float* __restrict__ rQm,
        const unsigned short* __restrict__ Mb, const unsigned short* __restrict__ Cbf,
        const unsigned short* __restrict__ Wb, const float* __restrict__ bres,
        float* __restrict__ outp) {
    __shared__ __align__(16) unsigned short Ps[64 * 256];  // e-vals -> F half [64 i][256 f]
    __shared__ __align__(16) unsigned short Ms[256 * 64];  // Sdt -> M chunks -> Cbf|W tiles
    __shared__ float Zp[4][64];
    __shared__ float rzs[64];
    int b = blockIdx.x >> 5, i0 = (blockIdx.x & 31) * 64;
    int tid = threadIdx.x, wv = tid >> 6, lane = tid & 63;
    int l15 = lane & 15, q = lane >> 4;

    // phase 0: stage SdotT tile [256 j][64 i] (linear)
#pragma unroll
    for (int k = 0; k < 8; ++k) {
        int G = k * 256 + tid;
        int j = G >> 3, g = G & 7;
        gld16(SdotT + ((size_t)(b * LQ_ + j)) * LC_ + i0 + g * 8, &Ms[G * 8]);
    }
    __syncthreads();
    // phase 1: lane owns i=lane; wave wv covers 64 j
    float z = 0.f;
    for (int jj = 0; jj < 64; ++jj) {
        int j = wv * 64 + jj;
        float s = b2f((short)Ms[j * 64 + lane]);
        float e = __expf(s + rQm[b * LQ_ + j]);
        z += e;
        *(unsigned short*)((char*)Ps + lane * 512 + (((j >> 3) ^ (lane & 7)) << 4)
            + (j & 7) * 2) = f2b(e);
    }
    Zp[wv][lane] = z;
    __syncthreads();
    if (tid < 64) rzs[tid] = 1.f / (Zp[0][tid] + Zp[1][tid] + Zp[2][tid] + Zp[3][tid]);

    // phase 2: acc = P @ M  (acc col c = wv*64+n*16+l15, row i = m*16+q*4+r)
    int r8 = lane >> 3, g8 = lane & 7;
    f32x4 acc[4][4];
#pragma unroll
    for (int m = 0; m < 4; ++m)
#pragma unroll
        for (int n = 0; n < 4; ++n) acc[m][n] = (f32x4){0.f, 0.f, 0.f, 0.f};
    for (int jc = 0; jc < 4; ++jc) {
        __syncthreads();
#pragma unroll
        for (int t = 0; t < 8; ++t) {
            int cb = wv * 64 + t * 8;
            int c = cb + r8;
            int gs = g8 ^ (c & 7);
            gld16(Mb + ((size_t)(b * 256 + c)) * LQ_ + jc * 64 + gs * 8, &Ms[cb * 64]);
        }
        __syncthreads();
#pragma unroll
        for (int kk = 0; kk < 2; ++kk) {
            bfrag av[4];
#pragma unroll
            for (int m = 0; m < 4; ++m) {
                int row = m * 16 + l15;
                int gp = (jc * 8 + kk * 4 + q) ^ (row & 7);
                av[m] = *(const bfrag*)((const char*)Ps + row * 512 + (gp << 4));
            }
#pragma unroll
            for (int n = 0; n < 4; ++n) {
                int c = wv * 64 + n * 16 + l15;
                int gb = (kk * 4 + q) ^ (c & 7);
                bfrag bv = *(const bfrag*)((const char*)Ms + c * 128 + (gb << 4));
#pragma unroll
                for (int m = 0; m < 4; ++m)
                    acc[m][n] = __builtin_amdgcn_mfma_f32_16x16x32_bf16(av[m], bv, acc[m][n], 0, 0, 0);
            }
        }
    }

    // ---- fused projection ----
    __syncthreads();  // Ps & Ms now dead
    unsigned short* CbfL = Ms;          // [128 d][64 i] swizzled, 16 KB
    unsigned short* WsL  = Ms + 8192;   // [128 d][64 k] swizzled, 16 KB
#pragma unroll
    for (int t = 0; t < 4; ++t) {
        int G = t * 256 + tid;
        int d = G >> 3, g = G & 7;
        gld16(Cbf + ((size_t)(b * D_ + d)) * LC_ + i0 + ((g ^ (d & 7)) << 3), &CbfL[G * 8]);
    }
    __syncthreads();

    f32x4 pacc[4][2];
#pragma unroll
    for (int m = 0; m < 4; ++m)
#pragma unroll
        for (int n = 0; n < 2; ++n) pacc[m][n] = (f32x4){0.f, 0.f, 0.f, 0.f};
    int wr = wv >> 1, wc = wv & 1;

#pragma unroll
    for (int fh = 0; fh < 2; ++fh) {
        // build F-half into Ps region: fh0 = [Ct | A], fh1 = [Ct*A | Ct*Bm]
        if (fh == 0) {
            if (wv < 2) {
#pragma unroll
                for (int m = 0; m < 4; ++m) {
                    int ibase = m * 16 + q * 4;
                    f4 rzv = *(const f4*)&rzs[ibase];
#pragma unroll
                    for (int n = 0; n < 4; ++n) {
                        int fc = 128 + wv * 64 + n * 16 + l15;
#pragma unroll
                        for (int r = 0; r < 4; ++r) {
                            int i = ibase + r;
                            *(unsigned short*)((char*)Ps + i * 512 +
                                (((fc >> 3) ^ (i & 7)) << 4) + (fc & 7) * 2)
                                = f2b(acc[m][n][r] * rzv[r]);
                        }
                    }
                }
            } else {
#pragma unroll
                for (int m = 0; m < 4; ++m) {
#pragma unroll
                    for (int n = 0; n < 4; ++n) {
                        int d = (wv - 2) * 64 + n * 16 + l15;
#pragma unroll
                        for (int r = 0; r < 4; ++r) {
                            int i = m * 16 + q * 4 + r;
                            unsigned short cv = *(const unsigned short*)((const char*)CbfL +
                                d * 128 + (((i >> 3) ^ (d & 7)) << 4) + (i & 7) * 2);
                            *(unsigned short*)((char*)Ps + i * 512 +
                                (((d >> 3) ^ (i & 7)) << 4) + (d & 7) * 2) = cv;
                        }
                    }
                }
            }
        } else {
#pragma unroll
            for (int m = 0; m < 4; ++m) {
                int ibase = m * 16 + q * 4;
                f4 rzv = *(const f4*)&rzs[ibase];
#pragma unroll
                for (int n = 0; n < 4; ++n) {
                    int c = wv * 64 + n * 16 + l15;  // fc = c; ct col = c & 127
                    int d = c & 127;
#pragma unroll
                    for (int r = 0; r < 4; ++r) {
                        int i = ibase + r;
                        float ct = b2f((short)*(const unsigned short*)((const char*)CbfL +
                            d * 128 + (((i >> 3) ^ (d & 7)) << 4) + (i & 7) * 2));
                        *(unsigned short*)((char*)Ps + i * 512 +
                            (((c >> 3) ^ (i & 7)) << 4) + (c & 7) * 2)
                            = f2b(ct * acc[m][n][r] * rzv[r]);
                    }
                }
            }
        }
        __syncthreads();  // F-half ready
#pragma unroll
        for (int kc = 0; kc < 4; ++kc) {
#pragma unroll
            for (int t = 0; t < 4; ++t) {
                int G = t * 256 + tid;
                int d = G >> 3, g = G & 7;
                gld16(Wb + (size_t)d * 512 + fh * 256 + kc * 64 + ((g ^ (d & 7)) << 3),
                      &WsL[G * 8]);
            }
            __syncthreads();
#pragma unroll
            for (int kk = 0; kk < 2; ++kk) {
                bfrag av[4];
#pragma unroll
                for (int m = 0; m < 4; ++m) {
                    int d = wr * 64 + m * 16 + l15;
                    av[m] = *(const bfrag*)((const char*)WsL + d * 128 +
                        (((kk * 4 + q) ^ (d & 7)) << 4));
                }
#pragma unroll
                for (int n = 0; n < 2; ++n) {
                    int i = wc * 32 + n * 16 + l15;
                    int gf = kc * 8 + kk * 4 + q;
                    bfrag bv = *(const bfrag*)((const char*)Ps + i * 512 +
                        ((gf ^ (i & 7)) << 4));
#pragma unroll
                    for (int m = 0; m < 4; ++m)
                        pacc[m][n] = __builtin_amdgcn_mfma_f32_16x16x32_bf16(av[m], bv, pacc[m][n], 0, 0, 0);
                }
            }
            __syncthreads();  // protect WsL (and Ps before F-half-2 rebuild)
        }
    }
    // epilogue: out = relu(pacc + bias)
#pragma unroll
    for (int m = 0; m < 4; ++m) {
        int dbase = wr * 64 + m * 16 + q * 4;
        f4 bias = *(const f4*)&bres[dbase];
#pragma unroll
        for (int n = 0; n < 2; ++n) {
            int i = i0 + wc * 32 + n * 16 + l15;
#pragma unroll
            for (int r = 0; r < 4; ++r) {
                float v = pacc[m][n][r] + bias[r];
                outp[((size_t)(b * D_ + dbase + r)) * LC_ + i] = fmaxf(v, 0.f);
            }
        }
    }
}

extern "C" void kernel_launch(void* const* d_in, const int* in_sizes, int n_in,
                              void* d_out, int out_size, void* d_ws, size_t ws_size,
                              hipStream_t stream) {
    const float* C = (const float*)d_in[0];
    const float* Q = (const float*)d_in[1];
    const int* cmask = (const int*)d_in[2];
    const int* qmask = (const int*)d_in[3];
    const float* w = (const float*)d_in[4];
    const float* W_res = (const float*)d_in[5];
    const float* b_res = (const float*)d_in[6];
    float* out = (float*)d_out;
    float* ws = (float*)d_ws;

    float* rC    = ws;                                   // 32768 f (mask folded)
    float* rQ    = rC + 32768;                           // 4096 f
    float* paz   = rQ + 4096;                            // 16384 f
    float* cwtp  = paz + 16384;                          // Cwt bf16 / part fp32 (2,097,152 f)
    float* wbf_f = cwtp + (size_t)2097152;               // Wb (32768 f)
    float* mb_f  = wbf_f + 32768;                        // Mb (524288 f)
    float* cbf_f = mb_f + 524288;                        // Cbf (2,097,152 f)
    float* sdt_f = cbf_f + (size_t)2097152;              // SdotT (4,194,304 f)
    float* qt_f  = sdt_f + (size_t)4194304;              // Qt (262,144 f)

    unsigned short* Cwt   = (unsigned short*)cwtp;
    float*          part  = cwtp;                        // alias: Cwt dead after k_sdotmm
    unsigned short* Wb    = (unsigned short*)wbf_f;
    unsigned short* Mb    = (unsigned short*)mb_f;
    unsigned short* Cbf   = (unsigned short*)cbf_f;
    unsigned short* SdotT = (unsigned short*)sdt_f;
    unsigned short* Qt    = (unsigned short*)qt_f;

    k_prepc<<<B_ * 32, 256, 0, stream>>>(C, w, cmask, W_res, Cbf, Cwt, Wb, rC);
    k_prepq<<<B_ * 4, 256, 0, stream>>>(Q, w, qmask, Qt, Mb, rQ);
    k_sdotmm<<<B_ * 32, 256, 0, stream>>>(Qt, Cwt, SdotT);
    k_sctcmm<<<B_ * 16, 256, 0, stream>>>(SdotT, rC, Cbf, part, paz);
    k_red<<<B_ * 8, 256, 0, stream>>>(part, paz, Mb);
    k_rowproj<<<B_ * 32, 256, 0, stream>>>(SdotT, rQ, Mb, Cbf, Wb, b_res, out);
}

// Round 8
// 79.471 us; speedup vs baseline: 8.9499x; 1.0634x over previous
//
#include <hip/hip_runtime.h>

// QANet block. B=16 D=128 LC=2048 LQ=256.
// R1: proj -> bf16 MFMA.                         711 -> 318 us
// R2: rowpass -> fused bf16 MFMA.                318 -> 159 us
// R3/R4: column path -> MFMA + bf16 (no max).    159 us
// R5: S -> MFMA (k_sdotmm), fp32 Sdot gone.      159 -> 100 us
// R6: fusion: 11 -> 6 dispatches, F in LDS.      100 -> 84.5 us
// R7: S recomputed in consumers; SdotT buffer + k_sdotmm killed; 4 dispatches:
//   k_prep   = prepc + prepq merged (branch on blockIdx)
//   k_sctcmm = S-MFMA chunk (QJ once + CW/chunk) + e-bounce + P.Cbf MFMA + z
//   k_red    unchanged
//   k_rowproj= S-MFMA (QA 64K + CB 16K in 80KB union) + row softmax + P@M + proj
// ws (floats): rC 32K | rQ 4K | paz 16K | part 2.1M | Wb 32K | Mb 0.5M |
//              Cbf 2.1M | Cwt 2.1M | Qt 0.13M  (~27.5 MB)

#define B_ 16
#define D_ 128
#define LC_ 2048
#define LQ_ 256
#define NEGV -1e30f

typedef float f4 __attribute__((ext_vector_type(4)));
typedef float f32x4 __attribute__((ext_vector_type(4)));
typedef short bfrag __attribute__((ext_vector_type(8)));
typedef unsigned short us4 __attribute__((ext_vector_type(4)));

__device__ __forceinline__ unsigned short f2b(float x) {
    unsigned u = __float_as_uint(x);
    u += 0x7fff + ((u >> 16) & 1);
    return (unsigned short)(u >> 16);
}

__device__ __forceinline__ float b2f(short s) {
    return __uint_as_float(((unsigned)(unsigned short)s) << 16);
}

__device__ __forceinline__ void gld16(const void* g, void* l) {
    __builtin_amdgcn_global_load_lds(
        (const __attribute__((address_space(1))) unsigned*)g,
        (__attribute__((address_space(3))) unsigned*)l, 16, 0, 0);
}

// merged prep: blocks [0,512): C-side; [512,576): Q-side
__global__ __launch_bounds__(256) void k_prep(const float* __restrict__ C,
        const float* __restrict__ Q, const float* __restrict__ w,
        const int* __restrict__ cmask, const int* __restrict__ qmask,
        const float* __restrict__ W_res,
        unsigned short* __restrict__ Cbf, unsigned short* __restrict__ Cwt,
        unsigned short* __restrict__ Qt, unsigned short* __restrict__ Mb,
        unsigned short* __restrict__ Wb, float* __restrict__ rC,
        float* __restrict__ rQ) {
    __shared__ float T[128][64];
    __shared__ float red[4][64];
    int tid = threadIdx.x;
    if (blockIdx.x < 512) {
        int b = blockIdx.x >> 5, i0 = (blockIdx.x & 31) * 64;
        int ii = tid & 63, db = tid >> 6;
        if (tid < 128) {
            int wo = blockIdx.x * 128 + tid;
            Wb[wo] = f2b(W_res[wo]);
        }
#pragma unroll
        for (int k = 0; k < 32; ++k) {
            int dd = db + 4 * k;
            float raw = C[((size_t)b * D_ + dd) * LC_ + i0 + ii];
            T[dd][ii] = raw;
            Cbf[((size_t)b * D_ + dd) * LC_ + i0 + ii] = f2b(raw);
        }
        __syncthreads();
        {
            float p = 0.f;
#pragma unroll
            for (int k = 0; k < 32; ++k) p += w[db * 32 + k] * T[db * 32 + k][ii];
            red[db][ii] = p;
        }
        int dq = db * 32;
#pragma unroll
        for (int m = 0; m < 8; ++m) {
            us4 v;
#pragma unroll
            for (int e = 0; e < 4; ++e) {
                int d = dq + m * 4 + e;
                v[e] = f2b(w[2 * D_ + d] * T[d][ii]);
            }
            *(us4*)&Cwt[((size_t)(b * LC_ + i0 + ii)) * D_ + dq + m * 4] = v;
        }
        __syncthreads();
        if (tid < 64) {
            int gi = b * LC_ + i0 + tid;
            rC[gi] = red[0][tid] + red[1][tid] + red[2][tid] + red[3][tid]
                   + (cmask[gi] ? 0.f : NEGV);
        }
    } else {
        int bq = blockIdx.x - 512;
        int b = bq >> 2, j0 = (bq & 3) * 64;
        int jj = tid & 63, db = tid >> 6;
#pragma unroll
        for (int k = 0; k < 32; ++k) {
            int dd = db + 4 * k;
            float raw = Q[((size_t)b * D_ + dd) * LQ_ + j0 + jj];
            T[dd][jj] = raw;
            Mb[((size_t)(b * 256 + dd)) * LQ_ + j0 + jj] = f2b(raw);
        }
        __syncthreads();
        {
            float p = 0.f;
#pragma unroll
            for (int k = 0; k < 32; ++k) p += w[D_ + db * 32 + k] * T[db * 32 + k][jj];
            red[db][jj] = p;
        }
        int dq = db * 32;
#pragma unroll
        for (int m = 0; m < 8; ++m) {
            us4 v;
#pragma unroll
            for (int e = 0; e < 4; ++e) v[e] = f2b(T[dq + m * 4 + e][jj]);
            *(us4*)&Qt[((size_t)(b * LQ_ + j0 + jj)) * D_ + dq + m * 4] = v;
        }
        __syncthreads();
        if (tid < 64) {
            int gj = b * LQ_ + j0 + tid;
            rQ[gj] = red[0][tid] + red[1][tid] + red[2][tid] + red[3][tid]
                   + (qmask[gj] ? 0.f : NEGV);
        }
    }
}

// S recomputed per chunk; part[ks][b][j][d] = sum_i exp(S^T+rcm)*Cbf; paz = z partials
__global__ __launch_bounds__(256) void k_sctcmm(
        const unsigned short* __restrict__ Qt, const unsigned short* __restrict__ Cwt,
        const float* __restrict__ rcm, const unsigned short* __restrict__ Cbf,
        float* __restrict__ part, float* __restrict__ paz) {
    __shared__ __align__(16) unsigned short QJ[64 * 128];  // [j][d] swz, 16 KB
    __shared__ __align__(16) unsigned short CW[64 * 128];  // [i][d] swz -> e-bounce, 16 KB
    __shared__ __align__(16) unsigned short Cs[128 * 64];  // Cbf [d][i] swz, 16 KB
    int bid = blockIdx.x;
    int ks = bid & 3, jt = (bid >> 2) & 3, b = bid >> 4;
    int j0 = jt * 64;
    int tid = threadIdx.x, wv = tid >> 6, lane = tid & 63;
    int jw = wv & 1, dw = wv >> 1;
    int l15 = lane & 15, q = lane >> 4;

    // stage QJ once (rows j0..j0+64)
#pragma unroll
    for (int t = 0; t < 4; ++t) {
        int G = t * 256 + tid;
        int j = G >> 4, g = G & 15;
        gld16(Qt + ((size_t)(b * LQ_ + j0 + j)) * D_ + ((g ^ (j & 7)) << 3), &QJ[G * 8]);
    }

    f32x4 acc[2][4];
#pragma unroll
    for (int mm = 0; mm < 2; ++mm)
#pragma unroll
        for (int nn = 0; nn < 4; ++nn) acc[mm][nn] = (f32x4){0.f, 0.f, 0.f, 0.f};
    float zac[4] = {0.f, 0.f, 0.f, 0.f};

    for (int c = 0; c < 8; ++c) {
        int ic = ks * 512 + c * 64;
        __syncthreads();  // prev chunk's CW/Cs readers done
#pragma unroll
        for (int t = 0; t < 4; ++t) {
            int G = t * 256 + tid;
            int i = G >> 4, g = G & 15;
            gld16(Cwt + ((size_t)(b * LC_ + ic + i)) * D_ + ((g ^ (i & 7)) << 3), &CW[G * 8]);
        }
#pragma unroll
        for (int t = 0; t < 4; ++t) {
            int G = t * 256 + tid;
            int d = G >> 3, g = G & 7;
            gld16(Cbf + ((size_t)(b * D_ + d)) * LC_ + ic + ((g ^ (d & 7)) << 3), &Cs[G * 8]);
        }
        __syncthreads();  // staging visible (QJ too on c==0)
        // S-MFMA: wave wv owns j-band wv*16..+16; sacc[n]: rows j=wv*16+q*4+r, col i=n*16+l15
        f32x4 sacc[4];
#pragma unroll
        for (int n = 0; n < 4; ++n) sacc[n] = (f32x4){0.f, 0.f, 0.f, 0.f};
#pragma unroll
        for (int ksd = 0; ksd < 4; ++ksd) {
            int jr = wv * 16 + l15;
            bfrag av = *(const bfrag*)&QJ[jr * 128 + (((ksd * 4 + q) ^ (jr & 7)) << 3)];
#pragma unroll
            for (int n = 0; n < 4; ++n) {
                int ir = n * 16 + l15;
                bfrag bv = *(const bfrag*)&CW[ir * 128 + (((ksd * 4 + q) ^ (ir & 7)) << 3)];
                sacc[n] = __builtin_amdgcn_mfma_f32_16x16x32_bf16(av, bv, sacc[n], 0, 0, 0);
            }
        }
        __syncthreads();  // CW S-reads done; rewrite as e-bounce
#pragma unroll
        for (int n = 0; n < 4; ++n) {
            int i = n * 16 + l15;
            float rc = rcm[b * LC_ + ic + i];
#pragma unroll
            for (int r = 0; r < 4; ++r) {
                int j = wv * 16 + q * 4 + r;
                float e = __expf(sacc[n][r] + rc);
                zac[r] += e;
                *(unsigned short*)((char*)CW + j * 128 +
                    (((i >> 3) ^ (j & 7)) << 4) + (i & 7) * 2) = f2b(e);
            }
        }
        __syncthreads();  // bounce visible
#pragma unroll
        for (int kk = 0; kk < 2; ++kk) {
            bfrag afr[2];
#pragma unroll
            for (int mm = 0; mm < 2; ++mm) {
                int j = jw * 32 + mm * 16 + l15;
                afr[mm] = *(const bfrag*)((const char*)CW + j * 128 +
                    (((kk * 4 + q) ^ (j & 7)) << 4));
            }
#pragma unroll
            for (int nn = 0; nn < 4; ++nn) {
                int d = dw * 64 + nn * 16 + l15;
                int g = kk * 4 + q;
                bfrag bv = *(const bfrag*)&Cs[d * 64 + ((g ^ (d & 7)) << 3)];
#pragma unroll
                for (int mm = 0; mm < 2; ++mm)
                    acc[mm][nn] = __builtin_amdgcn_mfma_f32_16x16x32_bf16(afr[mm], bv, acc[mm][nn], 0, 0, 0);
            }
        }
    }
    // z: reduce over l15 lanes (i coverage); j = wv*16 + q*4 + r
#pragma unroll
    for (int r = 0; r < 4; ++r) {
        zac[r] += __shfl_xor(zac[r], 1, 64);
        zac[r] += __shfl_xor(zac[r], 2, 64);
        zac[r] += __shfl_xor(zac[r], 4, 64);
        zac[r] += __shfl_xor(zac[r], 8, 64);
    }
    if (l15 == 0) {
#pragma unroll
        for (int r = 0; r < 4; ++r)
            paz[((size_t)(ks * B_ + b)) * LQ_ + j0 + wv * 16 + q * 4 + r] = zac[r];
    }
#pragma unroll
    for (int mm = 0; mm < 2; ++mm)
#pragma unroll
        for (int nn = 0; nn < 4; ++nn) {
            int d = dw * 64 + nn * 16 + l15;
#pragma unroll
            for (int r = 0; r < 4; ++r) {
                int j = j0 + jw * 32 + mm * 16 + q * 4 + r;
                part[((size_t)(ks * B_ + b) * LQ_ + j) * D_ + d] = acc[mm][nn][r];
            }
        }
}

// Mb[b][128+d][j] = bf16( sum_ks part / sum_ks paz )  via LDS transpose
__global__ __launch_bounds__(256) void k_red(const float* __restrict__ part,
        const float* __restrict__ paz, unsigned short* __restrict__ Mb) {
    __shared__ float Ts[64][68];
    int bid = blockIdx.x;
    int dt = bid & 1, jt = (bid >> 1) & 3, b = bid >> 3;
    int j0 = jt * 64, d0 = dt * 64;
    int tid = threadIdx.x;
    {
        int jj = tid >> 2, dq = (tid & 3) * 16;
        float zs = paz[((size_t)(0 * B_ + b)) * LQ_ + j0 + jj]
                 + paz[((size_t)(1 * B_ + b)) * LQ_ + j0 + jj]
                 + paz[((size_t)(2 * B_ + b)) * LQ_ + j0 + jj]
                 + paz[((size_t)(3 * B_ + b)) * LQ_ + j0 + jj];
        float rz = 1.0f / zs;
        f4 s[4];
#pragma unroll
        for (int q = 0; q < 4; ++q) s[q] = (f4){0.f, 0.f, 0.f, 0.f};
#pragma unroll
        for (int ks = 0; ks < 4; ++ks) {
            size_t base = ((size_t)(ks * B_ + b) * LQ_ + j0 + jj) * D_ + d0 + dq;
#pragma unroll
            for (int q = 0; q < 4; ++q) s[q] += *(const f4*)&part[base + q * 4];
        }
#pragma unroll
        for (int q = 0; q < 4; ++q) {
            f4 v = {s[q][0] * rz, s[q][1] * rz, s[q][2] * rz, s[q][3] * rz};
            *(f4*)&Ts[jj][dq + q * 4] = v;
        }
    }
    __syncthreads();
    {
        int dd = tid >> 2, jq = (tid & 3) * 16;
        us4 o0, o1, o2, o3;
#pragma unroll
        for (int q = 0; q < 4; ++q) o0[q] = f2b(Ts[jq + q][dd]);
#pragma unroll
        for (int q = 0; q < 4; ++q) o1[q] = f2b(Ts[jq + 4 + q][dd]);
#pragma unroll
        for (int q = 0; q < 4; ++q) o2[q] = f2b(Ts[jq + 8 + q][dd]);
#pragma unroll
        for (int q = 0; q < 4; ++q) o3[q] = f2b(Ts[jq + 12 + q][dd]);
        unsigned short* dst = Mb + ((size_t)(b * 256 + 128 + d0 + dd)) * LQ_ + j0 + jq;
        *(us4*)&dst[0] = o0; *(us4*)&dst[4] = o1; *(us4*)&dst[8] = o2; *(us4*)&dst[12] = o3;
    }
}

// Fused: S-MFMA -> row softmax -> [A|Bm]=P@M -> F in LDS -> out = relu(W.F + b)
__global__ __launch_bounds__(256) void k_rowproj(
        const unsigned short* __restrict__ Qt, const unsigned short* __restrict__ Cwt,
        const float* __restrict__ rQm, const unsigned short* __restrict__ Mb,
        const unsigned short* __restrict__ Cbf, const unsigned short* __restrict__ Wb,
        const float* __restrict__ bres, float* __restrict__ outp) {
    __shared__ __align__(16) unsigned short L[40960];  // 80 KB union
    unsigned short* QA   = L;            // ph0: Qt[256 j][128 d] swz (64 KB)
    unsigned short* CB   = L + 32768;    // ph0: Cwt[64 i][128 d] swz (16 KB)
    unsigned short* Ps   = L;            // e [64 i][256 j-gran] swz (32 KB)
    unsigned short* Ms   = L + 16384;    // M chunks [256 c][64 j] (32 KB)
    float*          Zp   = (float*)(L + 32768);  // [4][64] (over dead CB)
    unsigned short* CbfL = L + 32768;    // proj: Cbf [128 d][64 i] swz (16 KB)
    unsigned short* WsL  = L + 16384;    // proj: W [128 d][64 k] swz (16 KB)

    int b = blockIdx.x >> 5, i0 = (blockIdx.x & 31) * 64;
    int tid = threadIdx.x, wv = tid >> 6, lane = tid & 63;
    int l15 = lane & 15, q = lane >> 4;

    // ---- phase 0: stage QA + CB ----
#pragma unroll
    for (int k = 0; k < 16; ++k) {
        int G = k * 256 + tid;
        int j = G >> 4, g = G & 15;
        gld16(Qt + ((size_t)(b * LQ_ + j)) * D_ + ((g ^ (j & 7)) << 3), &QA[G * 8]);
    }
#pragma unroll
    for (int k = 0; k < 4; ++k) {
        int G = k * 256 + tid;
        int i = G >> 4, g = G & 15;
        gld16(Cwt + ((size_t)(b * LC_ + i0 + i)) * D_ + ((g ^ (i & 7)) << 3), &CB[G * 8]);
    }
    __syncthreads();
    // ---- S-MFMA: sacc[m][n]: rows j = wv*64+m*16+q*4+r, col i = n*16+l15 ----
    f32x4 sacc[4][4];
#pragma unroll
    for (int m = 0; m < 4; ++m)
#pragma unroll
        for (int n = 0; n < 4; ++n) sacc[m][n] = (f32x4){0.f, 0.f, 0.f, 0.f};
#pragma unroll
    for (int ksd = 0; ksd < 4; ++ksd) {
        bfrag av[4], bv[4];
#pragma unroll
        for (int m = 0; m < 4; ++m) {
            int jr = wv * 64 + m * 16 + l15;
            av[m] = *(const bfrag*)&QA[jr * 128 + (((ksd * 4 + q) ^ (jr & 7)) << 3)];
        }
#pragma unroll
        for (int n = 0; n < 4; ++n) {
            int ir = n * 16 + l15;
            bv[n] = *(const bfrag*)&CB[ir * 128 + (((ksd * 4 + q) ^ (ir & 7)) << 3)];
        }
#pragma unroll
        for (int m = 0; m < 4; ++m)
#pragma unroll
            for (int n = 0; n < 4; ++n)
                sacc[m][n] = __builtin_amdgcn_mfma_f32_16x16x32_bf16(av[m], bv[n], sacc[m][n], 0, 0, 0);
    }
    __syncthreads();  // QA/CB reads done
    // ---- e + z: Ps[i][j-gran swz], Zp[wv][i] partials ----
    float zp[4] = {0.f, 0.f, 0.f, 0.f};
#pragma unroll
    for (int m = 0; m < 4; ++m) {
        f4 rq4 = *(const f4*)&rQm[b * LQ_ + wv * 64 + m * 16 + q * 4];
#pragma unroll
        for (int n = 0; n < 4; ++n) {
            int i = n * 16 + l15;
#pragma unroll
            for (int r = 0; r < 4; ++r) {
                int j = wv * 64 + m * 16 + q * 4 + r;
                float e = __expf(sacc[m][n][r] + rq4[r]);
                zp[n] += e;
                *(unsigned short*)((char*)Ps + i * 512 +
                    (((j >> 3) ^ (i & 7)) << 4) + (j & 7) * 2) = f2b(e);
            }
        }
    }
#pragma unroll
    for (int n = 0; n < 4; ++n) {
        zp[n] += __shfl_xor(zp[n], 16, 64);
        zp[n] += __shfl_xor(zp[n], 32, 64);
    }
    if (q == 0) {
#pragma unroll
        for (int n = 0; n < 4; ++n) Zp[wv * 64 + n * 16 + l15] = zp[n];
    }
    __syncthreads();
    // rzv into registers (Zp region dies when CbfL is restaged)
    f4 rzv[4];
#pragma unroll
    for (int m = 0; m < 4; ++m)
#pragma unroll
        for (int r = 0; r < 4; ++r) {
            int i = m * 16 + q * 4 + r;
            rzv[m][r] = 1.f / (Zp[i] + Zp[64 + i] + Zp[128 + i] + Zp[192 + i]);
        }

    // ---- phase 2: acc = P @ M ----
    int r8 = lane >> 3, g8 = lane & 7;
    f32x4 acc[4][4];
#pragma unroll
    for (int m = 0; m < 4; ++m)
#pragma unroll
        for (int n = 0; n < 4; ++n) acc[m][n] = (f32x4){0.f, 0.f, 0.f, 0.f};
    for (int jc = 0; jc < 4; ++jc) {
        __syncthreads();
#pragma unroll
        for (int t = 0; t < 8; ++t) {
            int cb = wv * 64 + t * 8;
            int c = cb + r8;
            int gs = g8 ^ (c & 7);
            gld16(Mb + ((size_t)(b * 256 + c)) * LQ_ + jc * 64 + gs * 8, &Ms[cb * 64]);
        }
        __syncthreads();
#pragma unroll
        for (int kk = 0; kk < 2; ++kk) {
            bfrag av[4];
#pragma unroll
            for (int m = 0; m < 4; ++m) {
                int row = m * 16 + l15;
                int gp = (jc * 8 + kk * 4 + q) ^ (row & 7);
                av[m] = *(const bfrag*)((const char*)Ps + row * 512 + (gp << 4));
            }
#pragma unroll
            for (int n = 0; n < 4; ++n) {
                int c = wv * 64 + n * 16 + l15;
                int gb = (kk * 4 + q) ^ (c & 7);
                bfrag bv = *(const bfrag*)((const char*)Ms + c * 128 + (gb << 4));
#pragma unroll
                for (int m = 0; m < 4; ++m)
                    acc[m][n] = __builtin_amdgcn_mfma_f32_16x16x32_bf16(av[m], bv, acc[m][n], 0, 0, 0);
            }
        }
    }

    // ---- fused projection ----
    __syncthreads();  // Ps/Ms/Zp reads done
#pragma unroll
    for (int t = 0; t < 4; ++t) {
        int G = t * 256 + tid;
        int d = G >> 3, g = G & 7;
        gld16(Cbf + ((size_t)(b * D_ + d)) * LC_ + i0 + ((g ^ (d & 7)) << 3), &CbfL[G * 8]);
    }
    __syncthreads();

    f32x4 pacc[4][2];
#pragma unroll
    for (int m = 0; m < 4; ++m)
#pragma unroll
        for (int n = 0; n < 2; ++n) pacc[m][n] = (f32x4){0.f, 0.f, 0.f, 0.f};
    int wr = wv >> 1, wc = wv & 1;

#pragma unroll
    for (int fh = 0; fh < 2; ++fh) {
        if (fh == 0) {
            if (wv < 2) {
#pragma unroll
                for (int m = 0; m < 4; ++m) {
                    int ibase = m * 16 + q * 4;
#pragma unroll
                    for (int n = 0; n < 4; ++n) {
                        int fc = 128 + wv * 64 + n * 16 + l15;
#pragma unroll
                        for (int r = 0; r < 4; ++r) {
                            int i = ibase + r;
                            *(unsigned short*)((char*)Ps + i * 512 +
                                (((fc >> 3) ^ (i & 7)) << 4) + (fc & 7) * 2)
                                = f2b(acc[m][n][r] * rzv[m][r]);
                        }
                    }
                }
            } else {
#pragma unroll
                for (int m = 0; m < 4; ++m) {
#pragma unroll
                    for (int n = 0; n < 4; ++n) {
                        int d = (wv - 2) * 64 + n * 16 + l15;
#pragma unroll
                        for (int r = 0; r < 4; ++r) {
                            int i = m * 16 + q * 4 + r;
                            unsigned short cv = *(const unsigned short*)((const char*)CbfL +
                                d * 128 + (((i >> 3) ^ (d & 7)) << 4) + (i & 7) * 2);
                            *(unsigned short*)((char*)Ps + i * 512 +
                                (((d >> 3) ^ (i & 7)) << 4) + (d & 7) * 2) = cv;
                        }
                    }
                }
            }
        } else {
#pragma unroll
            for (int m = 0; m < 4; ++m) {
                int ibase = m * 16 + q * 4;
#pragma unroll
                for (int n = 0; n < 4; ++n) {
                    int c = wv * 64 + n * 16 + l15;
                    int d = c & 127;
#pragma unroll
                    for (int r = 0; r < 4; ++r) {
                        int i = ibase + r;
                        float ct = b2f((short)*(const unsigned short*)((const char*)CbfL +
                            d * 128 + (((i >> 3) ^ (d & 7)) << 4) + (i & 7) * 2));
                        *(unsigned short*)((char*)Ps + i * 512 +
                            (((c >> 3) ^ (i & 7)) << 4) + (c & 7) * 2)
                            = f2b(ct * acc[m][n][r] * rzv[m][r]);
                    }
                }
            }
        }
        __syncthreads();
#pragma unroll
        for (int kc = 0; kc < 4; ++kc) {
#pragma unroll
            for (int t = 0; t < 4; ++t) {
                int G = t * 256 + tid;
                int d = G >> 3, g = G & 7;
                gld16(Wb + (size_t)d * 512 + fh * 256 + kc * 64 + ((g ^ (d & 7)) << 3),
                      &WsL[G * 8]);
            }
            __syncthreads();
#pragma unroll
            for (int kk = 0; kk < 2; ++kk) {
                bfrag av[4];
#pragma unroll
                for (int m = 0; m < 4; ++m) {
                    int d = wr * 64 + m * 16 + l15;
                    av[m] = *(const bfrag*)((const char*)WsL + d * 128 +
                        (((kk * 4 + q) ^ (d & 7)) << 4));
                }
#pragma unroll
                for (int n = 0; n < 2; ++n) {
                    int i = wc * 32 + n * 16 + l15;
                    int gf = kc * 8 + kk * 4 + q;
                    bfrag bv = *(const bfrag*)((const char*)Ps + i * 512 +
                        ((gf ^ (i & 7)) << 4));
#pragma unroll
                    for (int m = 0; m < 4; ++m)
                        pacc[m][n] = __builtin_amdgcn_mfma_f32_16x16x32_bf16(av[m], bv, pacc[m][n], 0, 0, 0);
                }
            }
            __syncthreads();
        }
    }
#pragma unroll
    for (int m = 0; m < 4; ++m) {
        int dbase = wr * 64 + m * 16 + q * 4;
        f4 bias = *(const f4*)&bres[dbase];
#pragma unroll
        for (int n = 0; n < 2; ++n) {
            int i = i0 + wc * 32 + n * 16 + l15;
#pragma unroll
            for (int r = 0; r < 4; ++r) {
                float v = pacc[m][n][r] + bias[r];
                outp[((size_t)(b * D_ + dbase + r)) * LC_ + i] = fmaxf(v, 0.f);
            }
        }
    }
}

extern "C" void kernel_launch(void* const* d_in, const int* in_sizes, int n_in,
                              void* d_out, int out_size, void* d_ws, size_t ws_size,
                              hipStream_t stream) {
    const float* C = (const float*)d_in[0];
    const float* Q = (const float*)d_in[1];
    const int* cmask = (const int*)d_in[2];
    const int* qmask = (const int*)d_in[3];
    const float* w = (const float*)d_in[4];
    const float* W_res = (const float*)d_in[5];
    const float* b_res = (const float*)d_in[6];
    float* out = (float*)d_out;
    float* ws = (float*)d_ws;

    float* rC    = ws;                                   // 32768 f (mask folded)
    float* rQ    = rC + 32768;                           // 4096 f
    float* paz   = rQ + 4096;                            // 16384 f
    float* part  = paz + 16384;                          // 2,097,152 f
    float* wbf_f = part + (size_t)2097152;               // Wb (32768 f)
    float* mb_f  = wbf_f + 32768;                        // Mb (524288 f)
    float* cbf_f = mb_f + 524288;                        // Cbf (2,097,152 f)
    float* cwt_f = cbf_f + (size_t)2097152;              // Cwt (2,097,152 f)
    float* qt_f  = cwt_f + (size_t)2097152;              // Qt (131,072 f? -> 262,144 us)

    unsigned short* Wb  = (unsigned short*)wbf_f;
    unsigned short* Mb  = (unsigned short*)mb_f;
    unsigned short* Cbf = (unsigned short*)cbf_f;
    unsigned short* Cwt = (unsigned short*)cwt_f;
    unsigned short* Qt  = (unsigned short*)qt_f;

    k_prep<<<576, 256, 0, stream>>>(C, Q, w, cmask, qmask, W_res,
                                    Cbf, Cwt, Qt, Mb, Wb, rC, rQ);
    k_sctcmm<<<B_ * 16, 256, 0, stream>>>(Qt, Cwt, rC, Cbf, part, paz);
    k_red<<<B_ * 8, 256, 0, stream>>>(part, paz, Mb);
    k_rowproj<<<B_ * 32, 256, 0, stream>>>(Qt, Cwt, rQ, Mb, Cbf, Wb, b_res, out);
}